// Round 17
// baseline (643.579 us; speedup 1.0000x reference)
//
#include <hip/hip_runtime.h>

// ---------------- problem constants ----------------
#define B_  2
#define T_  2048
#define H_  2048
#define A_  2048
#define F_  8192
#define BT_ 4096   // B*T rows

typedef __bf16  bf16x8 __attribute__((ext_vector_type(8)));
typedef float   f32x4  __attribute__((ext_vector_type(4)));
typedef short   short8 __attribute__((ext_vector_type(8)));

__device__ __forceinline__ float bf2f(unsigned short b) {
  return __uint_as_float(((unsigned)b) << 16);
}
__device__ __forceinline__ unsigned short f2bf(float f) {
  unsigned u = __float_as_uint(f);
  unsigned r = (u + 0x7FFFu + ((u >> 16) & 1u)) >> 16;   // RNE
  return (unsigned short)r;
}

// global -> LDS direct copy, 16B per lane
typedef __attribute__((address_space(3))) void lds_void_t;
typedef __attribute__((address_space(1))) const void gc_void_t;
__device__ __forceinline__ void gload_lds16(const void* g, void* l) {
  __builtin_amdgcn_global_load_lds((gc_void_t*)g, (lds_void_t*)l, 16, 0, 0);
}

// ---------------- canary: ws too small diagnostic ----------------
__global__ void canary_kernel(float* out) { out[threadIdx.x] = 1000.0f; }

// ---------------- weight transpose + fp32->bf16 (z-batched, 2048x2048) ----------------
__global__ __launch_bounds__(256) void transpose5_kernel(
    const float* __restrict__ s0, const float* __restrict__ s1,
    const float* __restrict__ s2, const float* __restrict__ s3,
    const float* __restrict__ s4, unsigned short* __restrict__ dstbase)
{
  __shared__ float tile[32][33];
  const int z = blockIdx.z;
  const float* src = (z == 0) ? s0 : (z == 1) ? s1 : (z == 2) ? s2 : (z == 3) ? s3 : s4;
  unsigned short* dst = dstbase + (size_t)z * 2048 * 2048;
  const int tx = threadIdx.x & 31;
  const int ty = threadIdx.x >> 5;         // 0..7
  const int n0 = blockIdx.x * 32;
  const int k0 = blockIdx.y * 32;
#pragma unroll
  for (int i = 0; i < 32; i += 8)
    tile[ty + i][tx] = src[(size_t)(k0 + ty + i) * 2048 + n0 + tx];
  __syncthreads();
#pragma unroll
  for (int i = 0; i < 32; i += 8)
    dst[(size_t)(n0 + ty + i) * 2048 + k0 + tx] = f2bf(tile[tx][ty + i]);
}

// ---------------- weight transpose + fp32->bf16 (generic) ----------------
__global__ __launch_bounds__(256) void transpose_bf16_kernel(
    const float* __restrict__ src, unsigned short* __restrict__ dst, int Kd, int Nd)
{
  __shared__ float tile[32][33];
  const int tx = threadIdx.x & 31;
  const int ty = threadIdx.x >> 5;         // 0..7
  const int n0 = blockIdx.x * 32;
  const int k0 = blockIdx.y * 32;
#pragma unroll
  for (int i = 0; i < 32; i += 8)
    tile[ty + i][tx] = src[(size_t)(k0 + ty + i) * Nd + n0 + tx];
  __syncthreads();
#pragma unroll
  for (int i = 0; i < 32; i += 8)
    dst[(size_t)(n0 + ty + i) * Kd + k0 + tx] = f2bf(tile[tx][ty + i]);
}

// ---------------- block reduction (sum, sumsq) ----------------
__device__ __forceinline__ void block_reduce2(float& a, float& b) {
#pragma unroll
  for (int off = 32; off > 0; off >>= 1) {
    a += __shfl_down(a, off, 64);
    b += __shfl_down(b, off, 64);
  }
  __shared__ float sa[4], sb[4];
  const int lane = threadIdx.x & 63, w = threadIdx.x >> 6;
  __syncthreads();
  if (lane == 0) { sa[w] = a; sb[w] = b; }
  __syncthreads();
  a = sa[0] + sa[1] + sa[2] + sa[3];
  b = sb[0] + sb[1] + sb[2] + sb[3];
}

// ---------------- pre-LN + LN1 fused ----------------
__global__ __launch_bounds__(256) void ln_pre_kernel(
    const float* __restrict__ hidden,
    const float* __restrict__ pw, const float* __restrict__ pb,
    const float* __restrict__ w1, const float* __restrict__ b1,
    float* __restrict__ h0, unsigned short* __restrict__ x1)
{
  const int row = blockIdx.x, tid = threadIdx.x;
  const int c0 = tid * 8;
  const size_t base = (size_t)row * H_ + c0;
  float x[8];
  float4 v0 = *(const float4*)(hidden + base);
  float4 v1 = *(const float4*)(hidden + base + 4);
  x[0]=v0.x; x[1]=v0.y; x[2]=v0.z; x[3]=v0.w;
  x[4]=v1.x; x[5]=v1.y; x[6]=v1.z; x[7]=v1.w;
  float s = 0.f, s2 = 0.f;
#pragma unroll
  for (int j = 0; j < 8; ++j) { s += x[j]; s2 += x[j]*x[j]; }
  block_reduce2(s, s2);
  float mu  = s * (1.f / H_);
  float inv = rsqrtf(fmaxf(s2 * (1.f / H_) - mu*mu, 0.f) + 1e-5f);
  float y[8];
#pragma unroll
  for (int j = 0; j < 8; ++j) y[j] = (x[j] - mu) * inv * pw[c0+j] + pb[c0+j];
  *(float4*)(h0 + base)     = make_float4(y[0],y[1],y[2],y[3]);
  *(float4*)(h0 + base + 4) = make_float4(y[4],y[5],y[6],y[7]);
  s = 0.f; s2 = 0.f;
#pragma unroll
  for (int j = 0; j < 8; ++j) { s += y[j]; s2 += y[j]*y[j]; }
  block_reduce2(s, s2);
  mu  = s * (1.f / H_);
  inv = rsqrtf(fmaxf(s2 * (1.f / H_) - mu*mu, 0.f) + 1e-5f);
  unsigned o[4];
#pragma unroll
  for (int p = 0; p < 4; ++p) {
    unsigned lo = f2bf((y[2*p]   - mu) * inv * w1[c0+2*p]   + b1[c0+2*p]);
    unsigned hi = f2bf((y[2*p+1] - mu) * inv * w1[c0+2*p+1] + b1[c0+2*p+1]);
    o[p] = lo | (hi << 16);
  }
  *(uint4*)(x1 + base) = make_uint4(o[0], o[1], o[2], o[3]);
}

// ---------------- fused LN2 + FF token-shift mixes ----------------
__global__ __launch_bounds__(256) void lnmix2_kernel(
    const float* __restrict__ h1,
    const float* __restrict__ w_, const float* __restrict__ b_,
    const float* __restrict__ tmk_, const float* __restrict__ tmr_,
    unsigned short* __restrict__ kx2b, unsigned short* __restrict__ rx2b)
{
  const int row = blockIdx.x, tid = threadIdx.x;
  const int t = row & (T_ - 1);           // uniform per block
  const int c0 = tid * 8;
  const size_t base = (size_t)row * H_ + c0;
  float x[8], p[8];
  {
    float4 v0 = *(const float4*)(h1 + base);
    float4 v1 = *(const float4*)(h1 + base + 4);
    x[0]=v0.x; x[1]=v0.y; x[2]=v0.z; x[3]=v0.w;
    x[4]=v1.x; x[5]=v1.y; x[6]=v1.z; x[7]=v1.w;
  }
  const bool hasp = (t > 0);
  if (hasp) {
    float4 v0 = *(const float4*)(h1 + base - H_);
    float4 v1 = *(const float4*)(h1 + base - H_ + 4);
    p[0]=v0.x; p[1]=v0.y; p[2]=v0.z; p[3]=v0.w;
    p[4]=v1.x; p[5]=v1.y; p[6]=v1.z; p[7]=v1.w;
  } else {
#pragma unroll
    for (int j = 0; j < 8; ++j) p[j] = 0.f;
  }
  float s = 0.f, s2 = 0.f;
#pragma unroll
  for (int j = 0; j < 8; ++j) { s += x[j]; s2 += x[j]*x[j]; }
  block_reduce2(s, s2);
  const float mu  = s * (1.f / H_);
  const float inv = rsqrtf(fmaxf(s2 * (1.f / H_) - mu*mu, 0.f) + 1e-5f);
  float sp = 0.f, sp2 = 0.f;
#pragma unroll
  for (int j = 0; j < 8; ++j) { sp += p[j]; sp2 += p[j]*p[j]; }
  block_reduce2(sp, sp2);                  // uniform call; unused when !hasp
  const float mup  = sp * (1.f / H_);
  const float invp = rsqrtf(fmaxf(sp2 * (1.f / H_) - mup*mup, 0.f) + 1e-5f);
  unsigned ok[4], orr[4];
#pragma unroll
  for (int q = 0; q < 4; ++q) {
    unsigned ko = 0, ro = 0;
#pragma unroll
    for (int h = 0; h < 2; ++h) {
      const int j = q*2 + h;
      const float xr = (x[j] - mu) * inv * w_[c0+j] + b_[c0+j];
      const float cr = hasp ? (p[j] - mup) * invp * w_[c0+j] + b_[c0+j] : 0.f;
      ko |= (unsigned)f2bf(fmaf(xr - cr, tmk_[c0+j], cr)) << (h*16);
      ro |= (unsigned)f2bf(fmaf(xr - cr, tmr_[c0+j], cr)) << (h*16);
    }
    ok[q] = ko; orr[q] = ro;
  }
  *(uint4*)(kx2b + base) = make_uint4(ok[0],ok[1],ok[2],ok[3]);
  *(uint4*)(rx2b + base) = make_uint4(orr[0],orr[1],orr[2],orr[3]);
}

// ---------------- token-shift + mix (three outputs) ----------------
__global__ __launch_bounds__(256) void mix3_kernel(
    const unsigned short* __restrict__ x,
    const float* __restrict__ mk_, const float* __restrict__ mv_, const float* __restrict__ mr_,
    unsigned short* __restrict__ kx, unsigned short* __restrict__ vx, unsigned short* __restrict__ rx)
{
  const int row = blockIdx.x;
  const int t = row & (T_ - 1);
  const int c0 = threadIdx.x * 8;
  const size_t base = (size_t)row * H_ + c0;
  uint4 xv = *(const uint4*)(x + base);
  uint4 cv = make_uint4(0u,0u,0u,0u);
  if (t > 0) cv = *(const uint4*)(x + base - H_);
  const unsigned xs[4] = {xv.x, xv.y, xv.z, xv.w};
  const unsigned cs[4] = {cv.x, cv.y, cv.z, cv.w};
  unsigned ok[4], ov[4], orr[4];
#pragma unroll
  for (int p = 0; p < 4; ++p) {
    unsigned ko=0, vo=0, ro=0;
#pragma unroll
    for (int h = 0; h < 2; ++h) {
      const int j = p*2 + h;
      float xf = bf2f((unsigned short)((xs[p] >> (h*16)) & 0xFFFFu));
      float cf = bf2f((unsigned short)((cs[p] >> (h*16)) & 0xFFFFu));
      float d  = xf - cf;
      ko |= (unsigned)f2bf(fmaf(d, mk_[c0+j], cf)) << (h*16);
      vo |= (unsigned)f2bf(fmaf(d, mv_[c0+j], cf)) << (h*16);
      ro |= (unsigned)f2bf(fmaf(d, mr_[c0+j], cf)) << (h*16);
    }
    ok[p]=ko; ov[p]=vo; orr[p]=ro;
  }
  *(uint4*)(kx + base) = make_uint4(ok[0],ok[1],ok[2],ok[3]);
  *(uint4*)(vx + base) = make_uint4(ov[0],ov[1],ov[2],ov[3]);
  *(uint4*)(rx + base) = make_uint4(orr[0],orr[1],orr[2],orr[3]);
}

// ---------------- split-K combine: out += sigmoid(sig) * (P0 + P1) ----------------
__global__ __launch_bounds__(256) void sigcombine_kernel(
    const unsigned short* __restrict__ P0, const unsigned short* __restrict__ P1,
    const unsigned short* __restrict__ sigb, float* __restrict__ out)
{
  const size_t i8 = ((size_t)blockIdx.x * 256 + threadIdx.x) * 8;   // 8.4M elems / 8
  uint4 a = *(const uint4*)(P0 + i8);
  uint4 b = *(const uint4*)(P1 + i8);
  uint4 g = *(const uint4*)(sigb + i8);
  float4 o0 = *(const float4*)(out + i8);
  float4 o1 = *(const float4*)(out + i8 + 4);
  float r[8];
  const unsigned aw[4] = {a.x,a.y,a.z,a.w};
  const unsigned bw[4] = {b.x,b.y,b.z,b.w};
  const unsigned gw[4] = {g.x,g.y,g.z,g.w};
#pragma unroll
  for (int p = 0; p < 4; ++p)
#pragma unroll
    for (int h = 0; h < 2; ++h) {
      const float pv = bf2f((unsigned short)((aw[p] >> (h*16)) & 0xFFFFu))
                     + bf2f((unsigned short)((bw[p] >> (h*16)) & 0xFFFFu));
      const float sv = 1.f / (1.f + __expf(-bf2f((unsigned short)((gw[p] >> (h*16)) & 0xFFFFu))));
      r[p*2+h] = sv * pv;
    }
  o0.x += r[0]; o0.y += r[1]; o0.z += r[2]; o0.w += r[3];
  o1.x += r[4]; o1.y += r[5]; o1.z += r[6]; o1.w += r[7];
  *(float4*)(out + i8)     = o0;
  *(float4*)(out + i8 + 4) = o1;
}

// ---------------- chunked-parallel WKV scan ----------------
#define WKV_G 32   // channels per block
#define WKV_C 32   // chunks over T
#define WKV_L 64   // steps per chunk (WKV_C*WKV_L == T_)

__global__ __launch_bounds__(1024) void wkv_scan_kernel(
    const unsigned short* __restrict__ kg, const unsigned short* __restrict__ vg,
    const unsigned short* __restrict__ rg,
    const float* __restrict__ time_first, const float* __restrict__ time_decay,
    unsigned short* __restrict__ rwkv)
{
  const int tid = threadIdx.x;
  const int al  = tid & (WKV_G - 1);        // channel within group
  const int c   = tid >> 5;                 // chunk index 0..31
  const int b   = blockIdx.x >> 6;          // 64 groups per batch
  const int ag  = blockIdx.x & 63;
  const int a   = ag * WKV_G + al;
  const float tf = time_first[a];
  const float w  = -__expf(time_decay[a]);
  const size_t cb = (size_t)b * T_ * A_ + a + (size_t)c * WKV_L * A_;

  // ---- pass 1: per-chunk summary from zero state (k,v only) ----
  float aa = 0.f, bb = 0.f, pp = -1e38f;
  {
    float kb[4], vb[4];
#pragma unroll
    for (int j = 0; j < 4; ++j) {
      kb[j] = bf2f(kg[cb + (size_t)j * A_]);
      vb[j] = bf2f(vg[cb + (size_t)j * A_]);
    }
    for (int t0 = 0; t0 < WKV_L; t0 += 4) {
#pragma unroll
      for (int j = 0; j < 4; ++j) {
        const float kk = kb[j], vv = vb[j];
        const int tn = t0 + j + 4;
        if (tn < WKV_L) {
          kb[j] = bf2f(kg[cb + (size_t)tn * A_]);
          vb[j] = bf2f(vg[cb + (size_t)tn * A_]);
        }
        float ww2 = w + pp;
        float q2  = fmaxf(ww2, kk);
        float e1  = __expf(ww2 - q2);
        float e2  = __expf(kk  - q2);
        aa = e1*aa + e2*vv;
        bb = e1*bb + e2;
        pp = q2;
      }
    }
  }
  __shared__ float saa[WKV_C][WKV_G], sbb[WKV_C][WKV_G], spp[WKV_C][WKV_G];
  saa[c][al] = aa; sbb[c][al] = bb; spp[c][al] = pp;
  __syncthreads();

  // ---- combine: thread i (< WKV_G) walks chunks of channel i ----
  if (tid < WKV_G) {
    float Aa = 0.f, Bb = 0.f, Pp = -1e38f;
    const float Lw = (float)WKV_L * w;
    for (int cc = 0; cc < WKV_C; ++cc) {
      const float na = saa[cc][tid], nb = sbb[cc][tid], np = spp[cc][tid];
      saa[cc][tid] = Aa; sbb[cc][tid] = Bb; spp[cc][tid] = Pp;   // incoming prefix
      const float p1 = Pp + Lw;
      const float pc = fmaxf(p1, np);
      const float f1 = __expf(p1 - pc);
      const float f2 = __expf(np - pc);
      Aa = f1*Aa + f2*na;
      Bb = f1*Bb + f2*nb;
      Pp = pc;
    }
  }
  __syncthreads();
  aa = saa[c][al]; bb = sbb[c][al]; pp = spp[c][al];

  // ---- pass 2: outputs with true prefix state ----
  {
    float kb[4], vb[4], rb[4];
#pragma unroll
    for (int j = 0; j < 4; ++j) {
      kb[j] = bf2f(kg[cb + (size_t)j * A_]);
      vb[j] = bf2f(vg[cb + (size_t)j * A_]);
      rb[j] = bf2f(rg[cb + (size_t)j * A_]);
    }
    for (int t0 = 0; t0 < WKV_L; t0 += 4) {
#pragma unroll
      for (int j = 0; j < 4; ++j) {
        const float kk = kb[j], vv = vb[j], rr = rb[j];
        const int tn = t0 + j + 4;
        if (tn < WKV_L) {
          kb[j] = bf2f(kg[cb + (size_t)tn * A_]);
          vb[j] = bf2f(vg[cb + (size_t)tn * A_]);
          rb[j] = bf2f(rg[cb + (size_t)tn * A_]);
        }
        float ww = tf + kk;
        float q  = fmaxf(pp, ww);
        float e1 = __expf(pp - q);
        float e2 = __expf(ww - q);
        float o  = (e1*aa + e2*vv) / (e1*bb + e2);
        float sr = 1.f / (1.f + __expf(-rr));
        rwkv[cb + (size_t)(t0 + j) * A_] = f2bf(sr * o);
        float ww2 = w + pp;
        float q2  = fmaxf(ww2, kk);
        e1 = __expf(ww2 - q2);
        e2 = __expf(kk  - q2);
        aa = e1*aa + e2*vv;
        bb = e1*bb + e2;
        pp = q2;
      }
    }
  }
}

// ---------------- bf16 GEMM, BK=64, counted-vmcnt + frag-prefetch schedule ----------------
// A [M,lda] bf16 rm (reduction over K <= lda), Bt [N,lda] bf16 rm. BM x 256 tile,
// 512 thr, 8 waves (2M x 4N), per-wave (BM/2) x 64: FM = BM/32, FN = 4. NBUF LDS
// buffers; ONE barrier per K-tile (buffer swap). Counted vmcnt for NBUF=3 (6 loads
// stay in flight); NBUF=2 drains but last stage piece issued ~1 phase before wait.
// Both-sides 8-slot XOR swizzle on 128B rows (rule #21) -> conflict-free reads.
// BM=128 (r13): both kk-halves' 16 ds_reads up front, lgkm(8) -> 16 MFMA -> SP1 ->
// lgkm(0) -> 16 MFMA.  BM=256 (r14): sub-phase pipeline with counted lgkm.
// blockIdx.z batches independent GEMMs / split-K slices: byte strides azB/bzB/czB
// (lda decoupled from K enables split-K: A/B z-offset walks the K axis).
enum { EPI_BF16 = 0, EPI_ADDIP = 1, EPI_RELU2 = 2, EPI_SIGADD = 3 };

template <int BM, int NBUF, int RG, int CG, int EPI>
__global__ __launch_bounds__(512) void gemm4_kernel(
    const unsigned short* __restrict__ Ap, const unsigned short* __restrict__ Bp,
    void* __restrict__ Cp, int K, int Nn,
    const unsigned short* __restrict__ sigb,
    size_t azB, size_t bzB, size_t czB, int lda)
{
  constexpr int BN = 256;
  constexpr int FM = BM / 32;               // fragments per wave in M
  constexpr int FN = 4;
  __shared__ unsigned short As[NBUF * BM * 64];
  __shared__ unsigned short Bs[NBUF * BN * 64];
  const int zz = blockIdx.z;
  Ap = (const unsigned short*)((const char*)Ap + zz * azB);
  Bp = (const unsigned short*)((const char*)Bp + zz * bzB);
  Cp = (void*)((char*)Cp + zz * czB);
  const int tid  = threadIdx.x;
  const int lane = tid & 63;
  const int lr = lane & 15;
  const int hi = lane >> 4;                 // 0..3, selects 8-elem k-piece
  const int rx7 = lr & 7;                   // row&7 for fragment rows
  const int wid = tid >> 6;
  const int wm = wid >> 2, wn = wid & 3;    // 2M x 4N
  const int rowW = wm * (BM / 2);
  const int colW = wn * 64;
  // region-based XCD mapping (row-fastest within region)
  const int gx = gridDim.x;                 // col-tiles
  const int gy = gridDim.y;                 // row-tiles
  const int flat = blockIdx.y * gx + blockIdx.x;
  const int xcd = flat & 7;
  const int j = flat >> 3;                  // 0 .. RG*CG-1
  const int rgc = gy / RG;                  // row-group count (rgc * cgc == 8)
  const int r_idx = xcd % rgc;
  const int c_idx = xcd / rgc;
  const int row_l = j % RG;
  const int col_l = j / RG;
  const long row0 = (long)(r_idx * RG + row_l) * BM;
  const long col0 = (long)(c_idx * CG + col_l) * BN;
  const unsigned short* Ab = Ap + (size_t)row0 * lda;
  const unsigned short* Bb = Bp + (size_t)col0 * lda;
  const int srow8 = tid >> 3;               // 0..63
  const int sslot = (tid & 7) ^ (srow8 & 7);// permuted global source slot
  f32x4 acc[FM][FN] = {};

  // stage pieces:
  //  BM=128: SP0 = {A0, A1, B0} (3 loads), SP1 = {B1, B2, B3} (3 loads), 6/K-tile
  //  BM=256: SPq q=0..3: {A0A1},{A2A3},{B0B1},{B2B3} (2 loads each), 8/K-tile
  auto SP0 = [&](int bufi, int tt) {
    unsigned short* asb = As + bufi * (BM * 64);
    unsigned short* bsb = Bs + bufi * (BN * 64);
    const size_t ko = (size_t)tt * 64 + sslot * 8;
    gload_lds16(Ab + (size_t)srow8        * lda + ko, asb + tid * 8);
    gload_lds16(Ab + (size_t)(srow8 + 64) * lda + ko, asb + 4096 + tid * 8);
    gload_lds16(Bb + (size_t)srow8        * lda + ko, bsb + tid * 8);
  };
  auto SP1 = [&](int bufi, int tt) {
    unsigned short* bsb = Bs + bufi * (BN * 64);
    const size_t ko = (size_t)tt * 64 + sslot * 8;
    gload_lds16(Bb + (size_t)(srow8 + 64)  * lda + ko, bsb + 4096  + tid * 8);
    gload_lds16(Bb + (size_t)(srow8 + 128) * lda + ko, bsb + 8192  + tid * 8);
    gload_lds16(Bb + (size_t)(srow8 + 192) * lda + ko, bsb + 12288 + tid * 8);
  };
  auto SPq = [&](int bufi, int tt, int q) {
    const size_t ko = (size_t)tt * 64 + sslot * 8;
    if (q < 2) {
      unsigned short* asb = As + bufi * (BM * 64);
      gload_lds16(Ab + (size_t)(srow8 + q*128)      * lda + ko, asb + q*8192 + tid * 8);
      gload_lds16(Ab + (size_t)(srow8 + q*128 + 64) * lda + ko, asb + q*8192 + 4096 + tid * 8);
    } else {
      const int qq = q - 2;
      unsigned short* bsb = Bs + bufi * (BN * 64);
      gload_lds16(Bb + (size_t)(srow8 + qq*128)      * lda + ko, bsb + qq*8192 + tid * 8);
      gload_lds16(Bb + (size_t)(srow8 + qq*128 + 64) * lda + ko, bsb + qq*8192 + 4096 + tid * 8);
    }
  };

  const int nt = K >> 6;                    // K-tiles of 64
  if constexpr (BM == 128) {
    SP0(0, 0); SP1(0, 0);
    if constexpr (NBUF == 3) { SP0(1, 1); SP1(1, 1); }
  } else {
#pragma unroll
    for (int q = 0; q < 4; ++q) SPq(0, 0, q);
  }
  int cur = 0;
  for (int t = 0; t < nt; ++t) {
    if constexpr (NBUF == 3) {
      if (t + 1 < nt) asm volatile("s_waitcnt vmcnt(6)" ::: "memory");
      else            asm volatile("s_waitcnt vmcnt(0)" ::: "memory");
    } else {
      asm volatile("s_waitcnt vmcnt(0)" ::: "memory");
    }
    __builtin_amdgcn_s_barrier();           // ONLY barrier per K-tile (buffer swap)
    int nb = cur + (NBUF - 1); if (nb >= NBUF) nb -= NBUF;
    const unsigned short* asb = As + cur * (BM * 64);
    const unsigned short* bsb = Bs + cur * (BN * 64);
    if constexpr (BM == 128) {
      // r13 frag prefetch: issue BOTH kk-halves' reads, counted lgkm waits
      bf16x8 af0[4], bf0[4], af1[4], bf1[4];
      const int p0 = (0*4 + hi) ^ rx7;
      const int p1 = (1*4 + hi) ^ rx7;
#pragma unroll
      for (int m = 0; m < 4; ++m)
        af0[m] = __builtin_bit_cast(bf16x8,
            *(const short8*)(asb + (rowW + m*16 + lr) * 64 + p0*8));
#pragma unroll
      for (int n = 0; n < 4; ++n)
        bf0[n] = __builtin_bit_cast(bf16x8,
            *(const short8*)(bsb + (colW + n*16 + lr) * 64 + p0*8));
#pragma unroll
      for (int m = 0; m < 4; ++m)
        af1[m] = __builtin_bit_cast(bf16x8,
            *(const short8*)(asb + (rowW + m*16 + lr) * 64 + p1*8));
#pragma unroll
      for (int n = 0; n < 4; ++n)
        bf1[n] = __builtin_bit_cast(bf16x8,
            *(const short8*)(bsb + (colW + n*16 + lr) * 64 + p1*8));
      if (t + NBUF - 1 < nt) SP0(nb, t + NBUF - 1);
      asm volatile("s_waitcnt lgkmcnt(8)" ::: "memory");   // kk0's 8 reads done
      __builtin_amdgcn_sched_barrier(0);
      __builtin_amdgcn_s_setprio(1);
#pragma unroll
      for (int m = 0; m < 4; ++m)
#pragma unroll
        for (int n = 0; n < 4; ++n)
          acc[m][n] = __builtin_amdgcn_mfma_f32_16x16x32_bf16(af0[m], bf0[n], acc[m][n], 0, 0, 0);
      __builtin_amdgcn_s_setprio(0);
      if (t + NBUF - 1 < nt) SP1(nb, t + NBUF - 1);
      asm volatile("s_waitcnt lgkmcnt(0)" ::: "memory");   // kk1's reads done
      __builtin_amdgcn_sched_barrier(0);
      __builtin_amdgcn_s_setprio(1);
#pragma unroll
      for (int m = 0; m < 4; ++m)
#pragma unroll
        for (int n = 0; n < 4; ++n)
          acc[m][n] = __builtin_amdgcn_mfma_f32_16x16x32_bf16(af1[m], bf1[n], acc[m][n], 0, 0, 0);
      __builtin_amdgcn_s_setprio(0);
    } else {
      // sub-phase pipeline (r14): subs = (kk0,mh0),(kk0,mh1),(kk1,mh0),(kk1,mh1)
      bf16x8 aF[2][4], bF[2][4];
      const int p0 = (0*4 + hi) ^ rx7;
      const int p1 = (1*4 + hi) ^ rx7;
#pragma unroll
      for (int n = 0; n < 4; ++n)
        bF[0][n] = __builtin_bit_cast(bf16x8,
            *(const short8*)(bsb + (colW + n*16 + lr) * 64 + p0*8));
#pragma unroll
      for (int m = 0; m < 4; ++m)
        aF[0][m] = __builtin_bit_cast(bf16x8,
            *(const short8*)(asb + (rowW + m*16 + lr) * 64 + p0*8));
#pragma unroll
      for (int m = 0; m < 4; ++m)
        aF[1][m] = __builtin_bit_cast(bf16x8,
            *(const short8*)(asb + (rowW + (4+m)*16 + lr) * 64 + p0*8));
      if (t + 1 < nt) SPq(nb, t + 1, 0);
      asm volatile("s_waitcnt lgkmcnt(4)" ::: "memory");
      __builtin_amdgcn_sched_barrier(0);
      __builtin_amdgcn_s_setprio(1);
#pragma unroll
      for (int m = 0; m < 4; ++m)
#pragma unroll
        for (int n = 0; n < 4; ++n)
          acc[m][n] = __builtin_amdgcn_mfma_f32_16x16x32_bf16(aF[0][m], bF[0][n], acc[m][n], 0, 0, 0);
      __builtin_amdgcn_s_setprio(0);
#pragma unroll
      for (int n = 0; n < 4; ++n)
        bF[1][n] = __builtin_bit_cast(bf16x8,
            *(const short8*)(bsb + (colW + n*16 + lr) * 64 + p1*8));
#pragma unroll
      for (int m = 0; m < 4; ++m)
        aF[0][m] = __builtin_bit_cast(bf16x8,
            *(const short8*)(asb + (rowW + m*16 + lr) * 64 + p1*8));
      if (t + 1 < nt) SPq(nb, t + 1, 1);
      asm volatile("s_waitcnt lgkmcnt(8)" ::: "memory");
      __builtin_amdgcn_sched_barrier(0);
      __builtin_amdgcn_s_setprio(1);
#pragma unroll
      for (int m = 0; m < 4; ++m)
#pragma unroll
        for (int n = 0; n < 4; ++n)
          acc[4+m][n] = __builtin_amdgcn_mfma_f32_16x16x32_bf16(aF[1][m], bF[0][n], acc[4+m][n], 0, 0, 0);
      __builtin_amdgcn_s_setprio(0);
#pragma unroll
      for (int m = 0; m < 4; ++m)
        aF[1][m] = __builtin_bit_cast(bf16x8,
            *(const short8*)(asb + (rowW + (4+m)*16 + lr) * 64 + p1*8));
      if (t + 1 < nt) SPq(nb, t + 1, 2);
      asm volatile("s_waitcnt lgkmcnt(4)" ::: "memory");
      __builtin_amdgcn_sched_barrier(0);
      __builtin_amdgcn_s_setprio(1);
#pragma unroll
      for (int m = 0; m < 4; ++m)
#pragma unroll
        for (int n = 0; n < 4; ++n)
          acc[m][n] = __builtin_amdgcn_mfma_f32_16x16x32_bf16(aF[0][m], bF[1][n], acc[m][n], 0, 0, 0);
      __builtin_amdgcn_s_setprio(0);
      if (t + 1 < nt) SPq(nb, t + 1, 3);
      asm volatile("s_waitcnt lgkmcnt(0)" ::: "memory");
      __builtin_amdgcn_sched_barrier(0);
      __builtin_amdgcn_s_setprio(1);
#pragma unroll
      for (int m = 0; m < 4; ++m)
#pragma unroll
        for (int n = 0; n < 4; ++n)
          acc[4+m][n] = __builtin_amdgcn_mfma_f32_16x16x32_bf16(aF[1][m], bF[1][n], acc[4+m][n], 0, 0, 0);
      __builtin_amdgcn_s_setprio(0);
    }
    cur = (cur + 1 == NBUF) ? 0 : cur + 1;
  }

  // C/D layout: col = lane&15, row = (lane>>4)*4 + j
#pragma unroll
  for (int m = 0; m < FM; ++m) {
#pragma unroll
    for (int n = 0; n < FN; ++n) {
      const long col = col0 + colW + n*16 + lr;
#pragma unroll
      for (int j2 = 0; j2 < 4; ++j2) {
        const long row = row0 + rowW + m*16 + hi*4 + j2;
        const size_t idx = (size_t)row * Nn + col;
        const float v = acc[m][n][j2];
        if (EPI == EPI_BF16) {
          ((unsigned short*)Cp)[idx] = f2bf(v);
        } else if (EPI == EPI_ADDIP) {
          float* C = (float*)Cp;
          C[idx] = C[idx] + v;                       // in-place residual add
        } else if (EPI == EPI_RELU2) {
          float rr = v > 0.f ? v : 0.f;
          ((unsigned short*)Cp)[idx] = f2bf(rr * rr);
        } else {                                     // EPI_SIGADD
          float s = 1.f / (1.f + __expf(-bf2f(sigb[idx])));
          float* C = (float*)Cp;
          C[idx] = C[idx] + s * v;
        }
      }
    }
  }
}

// ---------------- workspace layout (MB) ----------------
// 0..48   mix3 outputs kx/vx/rx (16MB each)  -> later fWkT@0..32, fWvT@32..64
// 64..72  WkT   72..80 WvT   80..88 WrT   88..96 WoT   96..104 fWrT
// 104..120 S1 (x1 -> rwkv)
// 120..136 kbuf (k -> rx2)  136..152 vbuf (v -> r2pre)  152..184 PK (split-K partials,
//   aliases rbuf+M1 which are dead by SIGADD time; rbuf(152..168)=r, M1(168..184)=kx2)
// KK (kk2 [4096,8192] bf16, 64MB) aliases 64..128, all dead by the FF GEMMs.
#define MB(x) ((size_t)(x) << 20)
#define WS_NEED MB(184)

extern "C" void kernel_launch(void* const* d_in, const int* in_sizes, int n_in,
                              void* d_out, int out_size, void* d_ws, size_t ws_size,
                              hipStream_t stream) {
  const float* hidden     = (const float*)d_in[0];
  const float* pre_w      = (const float*)d_in[1];
  const float* pre_b      = (const float*)d_in[2];
  const float* ln1_w      = (const float*)d_in[3];
  const float* ln1_b      = (const float*)d_in[4];
  const float* ln2_w      = (const float*)d_in[5];
  const float* ln2_b      = (const float*)d_in[6];
  const float* time_decay = (const float*)d_in[7];
  const float* time_first = (const float*)d_in[8];
  const float* tmk        = (const float*)d_in[9];
  const float* tmv        = (const float*)d_in[10];
  const float* tmr        = (const float*)d_in[11];
  const float* Wk         = (const float*)d_in[12];
  const float* Wv         = (const float*)d_in[13];
  const float* Wr         = (const float*)d_in[14];
  const float* Wo         = (const float*)d_in[15];
  const float* f_tmk      = (const float*)d_in[16];
  const float* f_tmr      = (const float*)d_in[17];
  const float* f_Wk       = (const float*)d_in[18];
  const float* f_Wr       = (const float*)d_in[19];
  const float* f_Wv       = (const float*)d_in[20];
  float* out = (float*)d_out;
  char*  ws  = (char*)d_ws;

  if (ws_size < WS_NEED) {               // diagnostic canary: absmax ~1000 => ws too small
    canary_kernel<<<1, 256, 0, stream>>>(out);
    return;
  }

  unsigned short* MX   = (unsigned short*)(ws + MB(0));    // kx/vx/rx (3 x 16MB)
  unsigned short* fWkT = (unsigned short*)(ws + MB(0));    // after mixes dead
  unsigned short* fWvT = (unsigned short*)(ws + MB(32));
  unsigned short* WkT  = (unsigned short*)(ws + MB(64));   // Wk/Wv/Wr contiguous for z-stride
  unsigned short* WoT  = (unsigned short*)(ws + MB(88));
  unsigned short* fWrT = (unsigned short*)(ws + MB(96));
  unsigned short* KK   = (unsigned short*)(ws + MB(64));   // kk2 full, aliases dead data
  unsigned short* S1   = (unsigned short*)(ws + MB(104));  // x1 -> rwkv
  unsigned short* kbuf = (unsigned short*)(ws + MB(120));  // k -> rx2
  unsigned short* vbuf = (unsigned short*)(ws + MB(136));  // v -> r2pre
  unsigned short* rbuf = (unsigned short*)(ws + MB(152));  // r
  unsigned short* M1   = (unsigned short*)(ws + MB(168));  // kx2
  unsigned short* PK   = (unsigned short*)(ws + MB(152));  // split-K partials (2x16MB)

  const dim3 blk(256);
  const dim3 blk512(512);
  const dim3 gSmall(8, 32);      // 128x256 tile over [4096,2048] -> 256 blocks
  const dim3 gBig3(8, 16, 3);    // 256x256 tile, 3 batched projections -> 384 blocks
  const dim3 gBig2(8, 16, 2);    // 256x256 tile, split-K=2 -> 256 blocks
  const dim3 gRelu(32, 16);      // 256x256 tile over [4096,8192] -> 512 blocks

  // 1) five small weight transposes in ONE z=5 dispatch (dsts contiguous at 64+8z MB)
  transpose5_kernel<<<dim3(64, 64, 5), blk, 0, stream>>>(Wk, Wv, Wr, Wo, f_Wr, WkT);

  // 2) pre-LN + LN1: h0 -> d_out (fp32), x1 -> S1 (bf16)
  ln_pre_kernel<<<BT_, blk, 0, stream>>>(hidden, pre_w, pre_b, ln1_w, ln1_b, out, S1);

  // 3) one mix pass (kx/vx/rx) + one batched z=3 GEMM (256x256 tile, 25% less LDS/FLOP)
  mix3_kernel<<<BT_, blk, 0, stream>>>(S1, tmk, tmv, tmr, MX, MX + (MB(16)>>1), MX + (MB(32)>>1));
  gemm4_kernel<256,2,8,2,EPI_BF16><<<gBig3, blk512, 0, stream>>>(
      MX, WkT, kbuf, 2048, 2048, nullptr, MB(16), MB(8), MB(16), 2048);

  // 4) deferred big transposes (mix buffers now dead)
  transpose_bf16_kernel<<<dim3(256, 64), blk, 0, stream>>>(f_Wk, fWkT, 2048, 8192);
  transpose_bf16_kernel<<<dim3(64, 256), blk, 0, stream>>>(f_Wv, fWvT, 8192, 2048);

  // 5) chunk-parallel WKV scan + sigmoid(r)*wkv -> S1 (x1 dead)
  wkv_scan_kernel<<<dim3(128), dim3(1024), 0, stream>>>(kbuf, vbuf, rbuf, time_first, time_decay, S1);

  // 6) h1 = h0 + rwkv @ Wo  (in-place on d_out)
  gemm4_kernel<128,3,8,4,EPI_ADDIP><<<gSmall, blk512, 0, stream>>>(
      S1, WoT, out, 2048, 2048, nullptr, 0, 0, 0, 2048);

  // 7) fused LN2 + FF mixes: kx2 -> M1, rx2 -> kbuf (x2 never materialized)
  lnmix2_kernel<<<BT_, blk, 0, stream>>>(out, ln2_w, ln2_b, f_tmk, f_tmr, M1, kbuf);

  // 8) r2pre = rx2 @ f_Wr -> vbuf
  gemm4_kernel<128,3,8,4,EPI_BF16><<<gSmall, blk512, 0, stream>>>(
      kbuf, fWrT, vbuf, 2048, 2048, nullptr, 0, 0, 0, 2048);

  // 9) FF: kk2 = relu(kx2@f_Wk)^2 -> KK  (256x256 tile, sub-phase pipelined)
  gemm4_kernel<256,2,8,8,EPI_RELU2><<<gRelu, blk512, 0, stream>>>(
      M1, fWkT, KK, 2048, 8192, nullptr, 0, 0, 0, 2048);

  // 10) split-K=2: partials P{0,1} = kk2[:, z*4096:(z+1)*4096] @ f_WvT -> PK (bf16)
  //     (rbuf/M1 dead by now; full-machine 256 blocks; z walks the K axis via azB/bzB)
  gemm4_kernel<256,2,8,2,EPI_BF16><<<gBig2, blk512, 0, stream>>>(
      KK, fWvT, PK, 4096, 2048, nullptr, (size_t)4096*2, (size_t)4096*2, MB(16), 8192);

  // 11) out += sigmoid(r2pre) * (P0 + P1)
  sigcombine_kernel<<<dim3(4096), blk, 0, stream>>>(PK, PK + (MB(16)>>1), vbuf, out);
}

// Round 18
// 628.260 us; speedup vs baseline: 1.0244x; 1.0244x over previous
//
#include <hip/hip_runtime.h>

// ---------------- problem constants ----------------
#define B_  2
#define T_  2048
#define H_  2048
#define A_  2048
#define F_  8192
#define BT_ 4096   // B*T rows

typedef __bf16  bf16x8 __attribute__((ext_vector_type(8)));
typedef float   f32x4  __attribute__((ext_vector_type(4)));
typedef short   short8 __attribute__((ext_vector_type(8)));

__device__ __forceinline__ float bf2f(unsigned short b) {
  return __uint_as_float(((unsigned)b) << 16);
}
__device__ __forceinline__ unsigned short f2bf(float f) {
  unsigned u = __float_as_uint(f);
  unsigned r = (u + 0x7FFFu + ((u >> 16) & 1u)) >> 16;   // RNE
  return (unsigned short)r;
}

// global -> LDS direct copy, 16B per lane
typedef __attribute__((address_space(3))) void lds_void_t;
typedef __attribute__((address_space(1))) const void gc_void_t;
__device__ __forceinline__ void gload_lds16(const void* g, void* l) {
  __builtin_amdgcn_global_load_lds((gc_void_t*)g, (lds_void_t*)l, 16, 0, 0);
}

// ---------------- canary: ws too small diagnostic ----------------
__global__ void canary_kernel(float* out) { out[threadIdx.x] = 1000.0f; }

// ---------------- vectorized transpose + fp32->bf16 core (64x64 tile) ----------------
// src [Kd][Nd] fp32 rm -> dst [Nd][Kd] bf16 rm. float4 reads (16B/lane), 8B writes.
// LDS [64][65]: store side ~2-way, read side stride 260 = 4 mod 32 -> 2-way (free).
__device__ __forceinline__ void transpose_tile64(
    const float* __restrict__ src, unsigned short* __restrict__ dst,
    int Kd, int Nd, int bx, int by)
{
  __shared__ float tile[64][65];
  const int tx = threadIdx.x & 15;          // 16 col-groups of 4 floats
  const int ty = threadIdx.x >> 4;          // 16 rows per step
  const int n0 = bx * 64;                   // src col base
  const int k0 = by * 64;                   // src row base
#pragma unroll
  for (int i = 0; i < 64; i += 16) {
    float4 v = *(const float4*)(src + (size_t)(k0 + ty + i) * Nd + n0 + tx * 4);
    tile[ty + i][tx*4 + 0] = v.x;
    tile[ty + i][tx*4 + 1] = v.y;
    tile[ty + i][tx*4 + 2] = v.z;
    tile[ty + i][tx*4 + 3] = v.w;
  }
  __syncthreads();
#pragma unroll
  for (int i = 0; i < 64; i += 16) {
    const int r = ty + i;                   // dst-row offset (src col)
    unsigned short o[4];
#pragma unroll
    for (int c = 0; c < 4; ++c) o[c] = f2bf(tile[tx*4 + c][r]);
    *(uint2*)(dst + (size_t)(n0 + r) * Kd + k0 + tx * 4) =
        make_uint2((unsigned)o[0] | ((unsigned)o[1] << 16),
                   (unsigned)o[2] | ((unsigned)o[3] << 16));
  }
}

// z-batched 2048x2048 x5
__global__ __launch_bounds__(256) void transpose5_kernel(
    const float* __restrict__ s0, const float* __restrict__ s1,
    const float* __restrict__ s2, const float* __restrict__ s3,
    const float* __restrict__ s4, unsigned short* __restrict__ dstbase)
{
  const int z = blockIdx.z;
  const float* src = (z == 0) ? s0 : (z == 1) ? s1 : (z == 2) ? s2 : (z == 3) ? s3 : s4;
  unsigned short* dst = dstbase + (size_t)z * 2048 * 2048;
  transpose_tile64(src, dst, 2048, 2048, blockIdx.x, blockIdx.y);
}

// generic
__global__ __launch_bounds__(256) void transpose_bf16_kernel(
    const float* __restrict__ src, unsigned short* __restrict__ dst, int Kd, int Nd)
{
  transpose_tile64(src, dst, Kd, Nd, blockIdx.x, blockIdx.y);
}

// ---------------- block reduction (sum, sumsq) ----------------
__device__ __forceinline__ void block_reduce2(float& a, float& b) {
#pragma unroll
  for (int off = 32; off > 0; off >>= 1) {
    a += __shfl_down(a, off, 64);
    b += __shfl_down(b, off, 64);
  }
  __shared__ float sa[4], sb[4];
  const int lane = threadIdx.x & 63, w = threadIdx.x >> 6;
  __syncthreads();
  if (lane == 0) { sa[w] = a; sb[w] = b; }
  __syncthreads();
  a = sa[0] + sa[1] + sa[2] + sa[3];
  b = sb[0] + sb[1] + sb[2] + sb[3];
}

// ---------------- pre-LN + LN1 fused ----------------
__global__ __launch_bounds__(256) void ln_pre_kernel(
    const float* __restrict__ hidden,
    const float* __restrict__ pw, const float* __restrict__ pb,
    const float* __restrict__ w1, const float* __restrict__ b1,
    float* __restrict__ h0, unsigned short* __restrict__ x1)
{
  const int row = blockIdx.x, tid = threadIdx.x;
  const int c0 = tid * 8;
  const size_t base = (size_t)row * H_ + c0;
  float x[8];
  float4 v0 = *(const float4*)(hidden + base);
  float4 v1 = *(const float4*)(hidden + base + 4);
  x[0]=v0.x; x[1]=v0.y; x[2]=v0.z; x[3]=v0.w;
  x[4]=v1.x; x[5]=v1.y; x[6]=v1.z; x[7]=v1.w;
  float s = 0.f, s2 = 0.f;
#pragma unroll
  for (int j = 0; j < 8; ++j) { s += x[j]; s2 += x[j]*x[j]; }
  block_reduce2(s, s2);
  float mu  = s * (1.f / H_);
  float inv = rsqrtf(fmaxf(s2 * (1.f / H_) - mu*mu, 0.f) + 1e-5f);
  float y[8];
#pragma unroll
  for (int j = 0; j < 8; ++j) y[j] = (x[j] - mu) * inv * pw[c0+j] + pb[c0+j];
  *(float4*)(h0 + base)     = make_float4(y[0],y[1],y[2],y[3]);
  *(float4*)(h0 + base + 4) = make_float4(y[4],y[5],y[6],y[7]);
  s = 0.f; s2 = 0.f;
#pragma unroll
  for (int j = 0; j < 8; ++j) { s += y[j]; s2 += y[j]*y[j]; }
  block_reduce2(s, s2);
  mu  = s * (1.f / H_);
  inv = rsqrtf(fmaxf(s2 * (1.f / H_) - mu*mu, 0.f) + 1e-5f);
  unsigned o[4];
#pragma unroll
  for (int p = 0; p < 4; ++p) {
    unsigned lo = f2bf((y[2*p]   - mu) * inv * w1[c0+2*p]   + b1[c0+2*p]);
    unsigned hi = f2bf((y[2*p+1] - mu) * inv * w1[c0+2*p+1] + b1[c0+2*p+1]);
    o[p] = lo | (hi << 16);
  }
  *(uint4*)(x1 + base) = make_uint4(o[0], o[1], o[2], o[3]);
}

// ---------------- fused LN2 + FF token-shift mixes ----------------
__global__ __launch_bounds__(256) void lnmix2_kernel(
    const float* __restrict__ h1,
    const float* __restrict__ w_, const float* __restrict__ b_,
    const float* __restrict__ tmk_, const float* __restrict__ tmr_,
    unsigned short* __restrict__ kx2b, unsigned short* __restrict__ rx2b)
{
  const int row = blockIdx.x, tid = threadIdx.x;
  const int t = row & (T_ - 1);           // uniform per block
  const int c0 = tid * 8;
  const size_t base = (size_t)row * H_ + c0;
  float x[8], p[8];
  {
    float4 v0 = *(const float4*)(h1 + base);
    float4 v1 = *(const float4*)(h1 + base + 4);
    x[0]=v0.x; x[1]=v0.y; x[2]=v0.z; x[3]=v0.w;
    x[4]=v1.x; x[5]=v1.y; x[6]=v1.z; x[7]=v1.w;
  }
  const bool hasp = (t > 0);
  if (hasp) {
    float4 v0 = *(const float4*)(h1 + base - H_);
    float4 v1 = *(const float4*)(h1 + base - H_ + 4);
    p[0]=v0.x; p[1]=v0.y; p[2]=v0.z; p[3]=v0.w;
    p[4]=v1.x; p[5]=v1.y; p[6]=v1.z; p[7]=v1.w;
  } else {
#pragma unroll
    for (int j = 0; j < 8; ++j) p[j] = 0.f;
  }
  float s = 0.f, s2 = 0.f;
#pragma unroll
  for (int j = 0; j < 8; ++j) { s += x[j]; s2 += x[j]*x[j]; }
  block_reduce2(s, s2);
  const float mu  = s * (1.f / H_);
  const float inv = rsqrtf(fmaxf(s2 * (1.f / H_) - mu*mu, 0.f) + 1e-5f);
  float sp = 0.f, sp2 = 0.f;
#pragma unroll
  for (int j = 0; j < 8; ++j) { sp += p[j]; sp2 += p[j]*p[j]; }
  block_reduce2(sp, sp2);                  // uniform call; unused when !hasp
  const float mup  = sp * (1.f / H_);
  const float invp = rsqrtf(fmaxf(sp2 * (1.f / H_) - mup*mup, 0.f) + 1e-5f);
  unsigned ok[4], orr[4];
#pragma unroll
  for (int q = 0; q < 4; ++q) {
    unsigned ko = 0, ro = 0;
#pragma unroll
    for (int h = 0; h < 2; ++h) {
      const int j = q*2 + h;
      const float xr = (x[j] - mu) * inv * w_[c0+j] + b_[c0+j];
      const float cr = hasp ? (p[j] - mup) * invp * w_[c0+j] + b_[c0+j] : 0.f;
      ko |= (unsigned)f2bf(fmaf(xr - cr, tmk_[c0+j], cr)) << (h*16);
      ro |= (unsigned)f2bf(fmaf(xr - cr, tmr_[c0+j], cr)) << (h*16);
    }
    ok[q] = ko; orr[q] = ro;
  }
  *(uint4*)(kx2b + base) = make_uint4(ok[0],ok[1],ok[2],ok[3]);
  *(uint4*)(rx2b + base) = make_uint4(orr[0],orr[1],orr[2],orr[3]);
}

// ---------------- token-shift + mix (three outputs) ----------------
__global__ __launch_bounds__(256) void mix3_kernel(
    const unsigned short* __restrict__ x,
    const float* __restrict__ mk_, const float* __restrict__ mv_, const float* __restrict__ mr_,
    unsigned short* __restrict__ kx, unsigned short* __restrict__ vx, unsigned short* __restrict__ rx)
{
  const int row = blockIdx.x;
  const int t = row & (T_ - 1);
  const int c0 = threadIdx.x * 8;
  const size_t base = (size_t)row * H_ + c0;
  uint4 xv = *(const uint4*)(x + base);
  uint4 cv = make_uint4(0u,0u,0u,0u);
  if (t > 0) cv = *(const uint4*)(x + base - H_);
  const unsigned xs[4] = {xv.x, xv.y, xv.z, xv.w};
  const unsigned cs[4] = {cv.x, cv.y, cv.z, cv.w};
  unsigned ok[4], ov[4], orr[4];
#pragma unroll
  for (int p = 0; p < 4; ++p) {
    unsigned ko=0, vo=0, ro=0;
#pragma unroll
    for (int h = 0; h < 2; ++h) {
      const int j = p*2 + h;
      float xf = bf2f((unsigned short)((xs[p] >> (h*16)) & 0xFFFFu));
      float cf = bf2f((unsigned short)((cs[p] >> (h*16)) & 0xFFFFu));
      float d  = xf - cf;
      ko |= (unsigned)f2bf(fmaf(d, mk_[c0+j], cf)) << (h*16);
      vo |= (unsigned)f2bf(fmaf(d, mv_[c0+j], cf)) << (h*16);
      ro |= (unsigned)f2bf(fmaf(d, mr_[c0+j], cf)) << (h*16);
    }
    ok[p]=ko; ov[p]=vo; orr[p]=ro;
  }
  *(uint4*)(kx + base) = make_uint4(ok[0],ok[1],ok[2],ok[3]);
  *(uint4*)(vx + base) = make_uint4(ov[0],ov[1],ov[2],ov[3]);
  *(uint4*)(rx + base) = make_uint4(orr[0],orr[1],orr[2],orr[3]);
}

// ---------------- chunked-parallel WKV scan ----------------
#define WKV_G 32   // channels per block
#define WKV_C 32   // chunks over T
#define WKV_L 64   // steps per chunk (WKV_C*WKV_L == T_)

__global__ __launch_bounds__(1024) void wkv_scan_kernel(
    const unsigned short* __restrict__ kg, const unsigned short* __restrict__ vg,
    const unsigned short* __restrict__ rg,
    const float* __restrict__ time_first, const float* __restrict__ time_decay,
    unsigned short* __restrict__ rwkv)
{
  const int tid = threadIdx.x;
  const int al  = tid & (WKV_G - 1);        // channel within group
  const int c   = tid >> 5;                 // chunk index 0..31
  const int b   = blockIdx.x >> 6;          // 64 groups per batch
  const int ag  = blockIdx.x & 63;
  const int a   = ag * WKV_G + al;
  const float tf = time_first[a];
  const float w  = -__expf(time_decay[a]);
  const size_t cb = (size_t)b * T_ * A_ + a + (size_t)c * WKV_L * A_;

  // ---- pass 1: per-chunk summary from zero state (k,v only) ----
  float aa = 0.f, bb = 0.f, pp = -1e38f;
  {
    float kb[4], vb[4];
#pragma unroll
    for (int j = 0; j < 4; ++j) {
      kb[j] = bf2f(kg[cb + (size_t)j * A_]);
      vb[j] = bf2f(vg[cb + (size_t)j * A_]);
    }
    for (int t0 = 0; t0 < WKV_L; t0 += 4) {
#pragma unroll
      for (int j = 0; j < 4; ++j) {
        const float kk = kb[j], vv = vb[j];
        const int tn = t0 + j + 4;
        if (tn < WKV_L) {
          kb[j] = bf2f(kg[cb + (size_t)tn * A_]);
          vb[j] = bf2f(vg[cb + (size_t)tn * A_]);
        }
        float ww2 = w + pp;
        float q2  = fmaxf(ww2, kk);
        float e1  = __expf(ww2 - q2);
        float e2  = __expf(kk  - q2);
        aa = e1*aa + e2*vv;
        bb = e1*bb + e2;
        pp = q2;
      }
    }
  }
  __shared__ float saa[WKV_C][WKV_G], sbb[WKV_C][WKV_G], spp[WKV_C][WKV_G];
  saa[c][al] = aa; sbb[c][al] = bb; spp[c][al] = pp;
  __syncthreads();

  // ---- combine: thread i (< WKV_G) walks chunks of channel i ----
  if (tid < WKV_G) {
    float Aa = 0.f, Bb = 0.f, Pp = -1e38f;
    const float Lw = (float)WKV_L * w;
    for (int cc = 0; cc < WKV_C; ++cc) {
      const float na = saa[cc][tid], nb = sbb[cc][tid], np = spp[cc][tid];
      saa[cc][tid] = Aa; sbb[cc][tid] = Bb; spp[cc][tid] = Pp;   // incoming prefix
      const float p1 = Pp + Lw;
      const float pc = fmaxf(p1, np);
      const float f1 = __expf(p1 - pc);
      const float f2 = __expf(np - pc);
      Aa = f1*Aa + f2*na;
      Bb = f1*Bb + f2*nb;
      Pp = pc;
    }
  }
  __syncthreads();
  aa = saa[c][al]; bb = sbb[c][al]; pp = spp[c][al];

  // ---- pass 2: outputs with true prefix state ----
  {
    float kb[4], vb[4], rb[4];
#pragma unroll
    for (int j = 0; j < 4; ++j) {
      kb[j] = bf2f(kg[cb + (size_t)j * A_]);
      vb[j] = bf2f(vg[cb + (size_t)j * A_]);
      rb[j] = bf2f(rg[cb + (size_t)j * A_]);
    }
    for (int t0 = 0; t0 < WKV_L; t0 += 4) {
#pragma unroll
      for (int j = 0; j < 4; ++j) {
        const float kk = kb[j], vv = vb[j], rr = rb[j];
        const int tn = t0 + j + 4;
        if (tn < WKV_L) {
          kb[j] = bf2f(kg[cb + (size_t)tn * A_]);
          vb[j] = bf2f(vg[cb + (size_t)tn * A_]);
          rb[j] = bf2f(rg[cb + (size_t)tn * A_]);
        }
        float ww = tf + kk;
        float q  = fmaxf(pp, ww);
        float e1 = __expf(pp - q);
        float e2 = __expf(ww - q);
        float o  = (e1*aa + e2*vv) / (e1*bb + e2);
        float sr = 1.f / (1.f + __expf(-rr));
        rwkv[cb + (size_t)(t0 + j) * A_] = f2bf(sr * o);
        float ww2 = w + pp;
        float q2  = fmaxf(ww2, kk);
        e1 = __expf(ww2 - q2);
        e2 = __expf(kk  - q2);
        aa = e1*aa + e2*vv;
        bb = e1*bb + e2;
        pp = q2;
      }
    }
  }
}

// ---------------- bf16 GEMM, BK=64, counted-vmcnt + frag-prefetch schedule ----------------
// A [M,K] bf16 rm, Bt [N,K] bf16 rm. BM x 256 tile, 512 thr, 8 waves (2M x 4N),
// per-wave (BM/2) x 64: FM = BM/32, FN = 4. NBUF LDS buffers; ONE barrier per
// K-tile (buffer swap). Counted vmcnt for NBUF=3 (6 loads stay in flight); NBUF=2
// drains but last stage piece issued ~1 phase (>HBM latency) before the wait.
// Both-sides 8-slot XOR swizzle on 128B rows (rule #21) -> conflict-free reads.
// BM=128 (r13 schedule, best measured): both kk-halves' 16 ds_reads up front,
// lgkmcnt(8) -> 16 MFMA -> SP1 -> lgkmcnt(0) -> 16 MFMA.
// BM=256 (r14): sub-phase pipeline, each sub issues sub+1's reads, counted lgkm.
// blockIdx.z (optional) batches independent GEMMs: byte strides azB/bzB/czB.
enum { EPI_BF16 = 0, EPI_ADDIP = 1, EPI_RELU2 = 2, EPI_SIGADD = 3 };

template <int BM, int NBUF, int RG, int CG, int EPI>
__global__ __launch_bounds__(512) void gemm4_kernel(
    const unsigned short* __restrict__ Ap, const unsigned short* __restrict__ Bp,
    void* __restrict__ Cp, int K, int Nn,
    const unsigned short* __restrict__ sigb,
    size_t azB, size_t bzB, size_t czB)
{
  constexpr int BN = 256;
  constexpr int FM = BM / 32;               // fragments per wave in M
  constexpr int FN = 4;
  __shared__ unsigned short As[NBUF * BM * 64];
  __shared__ unsigned short Bs[NBUF * BN * 64];
  const int zz = blockIdx.z;
  Ap = (const unsigned short*)((const char*)Ap + zz * azB);
  Bp = (const unsigned short*)((const char*)Bp + zz * bzB);
  Cp = (void*)((char*)Cp + zz * czB);
  const int tid  = threadIdx.x;
  const int lane = tid & 63;
  const int lr = lane & 15;
  const int hi = lane >> 4;                 // 0..3, selects 8-elem k-piece
  const int rx7 = lr & 7;                   // row&7 for fragment rows
  const int wid = tid >> 6;
  const int wm = wid >> 2, wn = wid & 3;    // 2M x 4N
  const int rowW = wm * (BM / 2);
  const int colW = wn * 64;
  // region-based XCD mapping (row-fastest within region)
  const int gx = gridDim.x;                 // col-tiles
  const int gy = gridDim.y;                 // row-tiles
  const int flat = blockIdx.y * gx + blockIdx.x;
  const int xcd = flat & 7;
  const int j = flat >> 3;                  // 0 .. RG*CG-1
  const int rgc = gy / RG;                  // row-group count (rgc * cgc == 8)
  const int r_idx = xcd % rgc;
  const int c_idx = xcd / rgc;
  const int row_l = j % RG;
  const int col_l = j / RG;
  const long row0 = (long)(r_idx * RG + row_l) * BM;
  const long col0 = (long)(c_idx * CG + col_l) * BN;
  const unsigned short* Ab = Ap + (size_t)row0 * K;
  const unsigned short* Bb = Bp + (size_t)col0 * K;
  const int srow8 = tid >> 3;               // 0..63
  const int sslot = (tid & 7) ^ (srow8 & 7);// permuted global source slot
  f32x4 acc[FM][FN] = {};

  // stage pieces:
  //  BM=128: SP0 = {A0, A1, B0} (3 loads), SP1 = {B1, B2, B3} (3 loads), 6/K-tile
  //  BM=256: SPq q=0..3: {A0A1},{A2A3},{B0B1},{B2B3} (2 loads each), 8/K-tile
  auto SP0 = [&](int bufi, int tt) {
    unsigned short* asb = As + bufi * (BM * 64);
    unsigned short* bsb = Bs + bufi * (BN * 64);
    const size_t ko = (size_t)tt * 64 + sslot * 8;
    gload_lds16(Ab + (size_t)srow8        * K + ko, asb + tid * 8);
    gload_lds16(Ab + (size_t)(srow8 + 64) * K + ko, asb + 4096 + tid * 8);
    gload_lds16(Bb + (size_t)srow8        * K + ko, bsb + tid * 8);
  };
  auto SP1 = [&](int bufi, int tt) {
    unsigned short* bsb = Bs + bufi * (BN * 64);
    const size_t ko = (size_t)tt * 64 + sslot * 8;
    gload_lds16(Bb + (size_t)(srow8 + 64)  * K + ko, bsb + 4096  + tid * 8);
    gload_lds16(Bb + (size_t)(srow8 + 128) * K + ko, bsb + 8192  + tid * 8);
    gload_lds16(Bb + (size_t)(srow8 + 192) * K + ko, bsb + 12288 + tid * 8);
  };
  auto SPq = [&](int bufi, int tt, int q) {
    const size_t ko = (size_t)tt * 64 + sslot * 8;
    if (q < 2) {
      unsigned short* asb = As + bufi * (BM * 64);
      gload_lds16(Ab + (size_t)(srow8 + q*128)      * K + ko, asb + q*8192 + tid * 8);
      gload_lds16(Ab + (size_t)(srow8 + q*128 + 64) * K + ko, asb + q*8192 + 4096 + tid * 8);
    } else {
      const int qq = q - 2;
      unsigned short* bsb = Bs + bufi * (BN * 64);
      gload_lds16(Bb + (size_t)(srow8 + qq*128)      * K + ko, bsb + qq*8192 + tid * 8);
      gload_lds16(Bb + (size_t)(srow8 + qq*128 + 64) * K + ko, bsb + qq*8192 + 4096 + tid * 8);
    }
  };

  const int nt = K >> 6;                    // K-tiles of 64
  if constexpr (BM == 128) {
    SP0(0, 0); SP1(0, 0);
    if constexpr (NBUF == 3) { SP0(1, 1); SP1(1, 1); }
  } else {
#pragma unroll
    for (int q = 0; q < 4; ++q) SPq(0, 0, q);
  }
  int cur = 0;
  for (int t = 0; t < nt; ++t) {
    if constexpr (NBUF == 3) {
      if (t + 1 < nt) asm volatile("s_waitcnt vmcnt(6)" ::: "memory");
      else            asm volatile("s_waitcnt vmcnt(0)" ::: "memory");
    } else {
      asm volatile("s_waitcnt vmcnt(0)" ::: "memory");
    }
    __builtin_amdgcn_s_barrier();           // ONLY barrier per K-tile (buffer swap)
    int nb = cur + (NBUF - 1); if (nb >= NBUF) nb -= NBUF;
    const unsigned short* asb = As + cur * (BM * 64);
    const unsigned short* bsb = Bs + cur * (BN * 64);
    if constexpr (BM == 128) {
      // r13 frag prefetch: issue BOTH kk-halves' reads, counted lgkm waits
      bf16x8 af0[4], bf0[4], af1[4], bf1[4];
      const int p0 = (0*4 + hi) ^ rx7;
      const int p1 = (1*4 + hi) ^ rx7;
#pragma unroll
      for (int m = 0; m < 4; ++m)
        af0[m] = __builtin_bit_cast(bf16x8,
            *(const short8*)(asb + (rowW + m*16 + lr) * 64 + p0*8));
#pragma unroll
      for (int n = 0; n < 4; ++n)
        bf0[n] = __builtin_bit_cast(bf16x8,
            *(const short8*)(bsb + (colW + n*16 + lr) * 64 + p0*8));
#pragma unroll
      for (int m = 0; m < 4; ++m)
        af1[m] = __builtin_bit_cast(bf16x8,
            *(const short8*)(asb + (rowW + m*16 + lr) * 64 + p1*8));
#pragma unroll
      for (int n = 0; n < 4; ++n)
        bf1[n] = __builtin_bit_cast(bf16x8,
            *(const short8*)(bsb + (colW + n*16 + lr) * 64 + p1*8));
      if (t + NBUF - 1 < nt) SP0(nb, t + NBUF - 1);
      asm volatile("s_waitcnt lgkmcnt(8)" ::: "memory");   // kk0's 8 reads done
      __builtin_amdgcn_sched_barrier(0);
      __builtin_amdgcn_s_setprio(1);
#pragma unroll
      for (int m = 0; m < 4; ++m)
#pragma unroll
        for (int n = 0; n < 4; ++n)
          acc[m][n] = __builtin_amdgcn_mfma_f32_16x16x32_bf16(af0[m], bf0[n], acc[m][n], 0, 0, 0);
      __builtin_amdgcn_s_setprio(0);
      if (t + NBUF - 1 < nt) SP1(nb, t + NBUF - 1);
      asm volatile("s_waitcnt lgkmcnt(0)" ::: "memory");   // kk1's reads done
      __builtin_amdgcn_sched_barrier(0);
      __builtin_amdgcn_s_setprio(1);
#pragma unroll
      for (int m = 0; m < 4; ++m)
#pragma unroll
        for (int n = 0; n < 4; ++n)
          acc[m][n] = __builtin_amdgcn_mfma_f32_16x16x32_bf16(af1[m], bf1[n], acc[m][n], 0, 0, 0);
      __builtin_amdgcn_s_setprio(0);
    } else {
      // sub-phase pipeline (r14): subs = (kk0,mh0),(kk0,mh1),(kk1,mh0),(kk1,mh1)
      bf16x8 aF[2][4], bF[2][4];
      const int p0 = (0*4 + hi) ^ rx7;
      const int p1 = (1*4 + hi) ^ rx7;
#pragma unroll
      for (int n = 0; n < 4; ++n)
        bF[0][n] = __builtin_bit_cast(bf16x8,
            *(const short8*)(bsb + (colW + n*16 + lr) * 64 + p0*8));
#pragma unroll
      for (int m = 0; m < 4; ++m)
        aF[0][m] = __builtin_bit_cast(bf16x8,
            *(const short8*)(asb + (rowW + m*16 + lr) * 64 + p0*8));
#pragma unroll
      for (int m = 0; m < 4; ++m)
        aF[1][m] = __builtin_bit_cast(bf16x8,
            *(const short8*)(asb + (rowW + (4+m)*16 + lr) * 64 + p0*8));
      if (t + 1 < nt) SPq(nb, t + 1, 0);
      asm volatile("s_waitcnt lgkmcnt(4)" ::: "memory");
      __builtin_amdgcn_sched_barrier(0);
      __builtin_amdgcn_s_setprio(1);
#pragma unroll
      for (int m = 0; m < 4; ++m)
#pragma unroll
        for (int n = 0; n < 4; ++n)
          acc[m][n] = __builtin_amdgcn_mfma_f32_16x16x32_bf16(aF[0][m], bF[0][n], acc[m][n], 0, 0, 0);
      __builtin_amdgcn_s_setprio(0);
#pragma unroll
      for (int n = 0; n < 4; ++n)
        bF[1][n] = __builtin_bit_cast(bf16x8,
            *(const short8*)(bsb + (colW + n*16 + lr) * 64 + p1*8));
#pragma unroll
      for (int m = 0; m < 4; ++m)
        aF[0][m] = __builtin_bit_cast(bf16x8,
            *(const short8*)(asb + (rowW + m*16 + lr) * 64 + p1*8));
      if (t + 1 < nt) SPq(nb, t + 1, 1);
      asm volatile("s_waitcnt lgkmcnt(8)" ::: "memory");
      __builtin_amdgcn_sched_barrier(0);
      __builtin_amdgcn_s_setprio(1);
#pragma unroll
      for (int m = 0; m < 4; ++m)
#pragma unroll
        for (int n = 0; n < 4; ++n)
          acc[4+m][n] = __builtin_amdgcn_mfma_f32_16x16x32_bf16(aF[1][m], bF[0][n], acc[4+m][n], 0, 0, 0);
      __builtin_amdgcn_s_setprio(0);
#pragma unroll
      for (int m = 0; m < 4; ++m)
        aF[1][m] = __builtin_bit_cast(bf16x8,
            *(const short8*)(asb + (rowW + (4+m)*16 + lr) * 64 + p1*8));
      if (t + 1 < nt) SPq(nb, t + 1, 2);
      asm volatile("s_waitcnt lgkmcnt(4)" ::: "memory");
      __builtin_amdgcn_sched_barrier(0);
      __builtin_amdgcn_s_setprio(1);
#pragma unroll
      for (int m = 0; m < 4; ++m)
#pragma unroll
        for (int n = 0; n < 4; ++n)
          acc[m][n] = __builtin_amdgcn_mfma_f32_16x16x32_bf16(aF[0][m], bF[1][n], acc[m][n], 0, 0, 0);
      __builtin_amdgcn_s_setprio(0);
      if (t + 1 < nt) SPq(nb, t + 1, 3);
      asm volatile("s_waitcnt lgkmcnt(0)" ::: "memory");
      __builtin_amdgcn_sched_barrier(0);
      __builtin_amdgcn_s_setprio(1);
#pragma unroll
      for (int m = 0; m < 4; ++m)
#pragma unroll
        for (int n = 0; n < 4; ++n)
          acc[4+m][n] = __builtin_amdgcn_mfma_f32_16x16x32_bf16(aF[1][m], bF[1][n], acc[4+m][n], 0, 0, 0);
      __builtin_amdgcn_s_setprio(0);
    }
    cur = (cur + 1 == NBUF) ? 0 : cur + 1;
  }

  // C/D layout: col = lane&15, row = (lane>>4)*4 + j
#pragma unroll
  for (int m = 0; m < FM; ++m) {
#pragma unroll
    for (int n = 0; n < FN; ++n) {
      const long col = col0 + colW + n*16 + lr;
#pragma unroll
      for (int j2 = 0; j2 < 4; ++j2) {
        const long row = row0 + rowW + m*16 + hi*4 + j2;
        const size_t idx = (size_t)row * Nn + col;
        const float v = acc[m][n][j2];
        if (EPI == EPI_BF16) {
          ((unsigned short*)Cp)[idx] = f2bf(v);
        } else if (EPI == EPI_ADDIP) {
          float* C = (float*)Cp;
          C[idx] = C[idx] + v;                       // in-place residual add
        } else if (EPI == EPI_RELU2) {
          float rr = v > 0.f ? v : 0.f;
          ((unsigned short*)Cp)[idx] = f2bf(rr * rr);
        } else {                                     // EPI_SIGADD
          float s = 1.f / (1.f + __expf(-bf2f(sigb[idx])));
          float* C = (float*)Cp;
          C[idx] = C[idx] + s * v;
        }
      }
    }
  }
}

// ---------------- workspace layout (MB) ----------------
// 0..48   mix3 outputs kx/vx/rx (16MB each)  -> later fWkT@0..32, fWvT@32..64
// 64..72  WkT   72..80 WvT   80..88 WrT   88..96 WoT   96..104 fWrT
// 104..120 S1 (x1 -> rwkv)
// 120..136 kbuf (k -> rx2)  136..152 vbuf (v -> r2pre)  152..168 rbuf (r)
// 168..184 M1 (kx2)
// KK (kk2 [4096,8192] bf16, 64MB) aliases 64..128, all dead by the FF GEMMs.
#define MB(x) ((size_t)(x) << 20)
#define WS_NEED MB(184)

extern "C" void kernel_launch(void* const* d_in, const int* in_sizes, int n_in,
                              void* d_out, int out_size, void* d_ws, size_t ws_size,
                              hipStream_t stream) {
  const float* hidden     = (const float*)d_in[0];
  const float* pre_w      = (const float*)d_in[1];
  const float* pre_b      = (const float*)d_in[2];
  const float* ln1_w      = (const float*)d_in[3];
  const float* ln1_b      = (const float*)d_in[4];
  const float* ln2_w      = (const float*)d_in[5];
  const float* ln2_b      = (const float*)d_in[6];
  const float* time_decay = (const float*)d_in[7];
  const float* time_first = (const float*)d_in[8];
  const float* tmk        = (const float*)d_in[9];
  const float* tmv        = (const float*)d_in[10];
  const float* tmr        = (const float*)d_in[11];
  const float* Wk         = (const float*)d_in[12];
  const float* Wv         = (const float*)d_in[13];
  const float* Wr         = (const float*)d_in[14];
  const float* Wo         = (const float*)d_in[15];
  const float* f_tmk      = (const float*)d_in[16];
  const float* f_tmr      = (const float*)d_in[17];
  const float* f_Wk       = (const float*)d_in[18];
  const float* f_Wr       = (const float*)d_in[19];
  const float* f_Wv       = (const float*)d_in[20];
  float* out = (float*)d_out;
  char*  ws  = (char*)d_ws;

  if (ws_size < WS_NEED) {               // diagnostic canary: absmax ~1000 => ws too small
    canary_kernel<<<1, 256, 0, stream>>>(out);
    return;
  }

  unsigned short* MX   = (unsigned short*)(ws + MB(0));    // kx/vx/rx (3 x 16MB)
  unsigned short* fWkT = (unsigned short*)(ws + MB(0));    // after mixes dead
  unsigned short* fWvT = (unsigned short*)(ws + MB(32));
  unsigned short* WkT  = (unsigned short*)(ws + MB(64));   // Wk/Wv/Wr contiguous for z-stride
  unsigned short* WoT  = (unsigned short*)(ws + MB(88));
  unsigned short* fWrT = (unsigned short*)(ws + MB(96));
  unsigned short* KK   = (unsigned short*)(ws + MB(64));   // kk2 full, aliases dead data
  unsigned short* S1   = (unsigned short*)(ws + MB(104));  // x1 -> rwkv
  unsigned short* kbuf = (unsigned short*)(ws + MB(120));  // k -> rx2
  unsigned short* vbuf = (unsigned short*)(ws + MB(136));  // v -> r2pre
  unsigned short* rbuf = (unsigned short*)(ws + MB(152));  // r
  unsigned short* M1   = (unsigned short*)(ws + MB(168));  // kx2

  const dim3 blk(256);
  const dim3 blk512(512);
  const dim3 gSmall(8, 32);      // 128x256 tile over [4096,2048] -> 256 blocks
  const dim3 gSmall3(8, 32, 3);  // 3 batched projections
  const dim3 gRelu(32, 16);      // 256x256 tile over [4096,8192] -> 512 blocks

  // 1) five small weight transposes in ONE z=5 dispatch (vectorized 64x64 tiles)
  transpose5_kernel<<<dim3(32, 32, 5), blk, 0, stream>>>(Wk, Wv, Wr, Wo, f_Wr, WkT);

  // 2) pre-LN + LN1: h0 -> d_out (fp32), x1 -> S1 (bf16)
  ln_pre_kernel<<<BT_, blk, 0, stream>>>(hidden, pre_w, pre_b, ln1_w, ln1_b, out, S1);

  // 3) one mix pass (kx/vx/rx) + one batched z=3 GEMM: {k,v,r} = mix @ {Wk,Wv,Wr}^T
  mix3_kernel<<<BT_, blk, 0, stream>>>(S1, tmk, tmv, tmr, MX, MX + (MB(16)>>1), MX + (MB(32)>>1));
  gemm4_kernel<128,3,8,4,EPI_BF16><<<gSmall3, blk512, 0, stream>>>(
      MX, WkT, kbuf, 2048, 2048, nullptr, MB(16), MB(8), MB(16));

  // 4) deferred big transposes (mix buffers now dead), vectorized
  transpose_bf16_kernel<<<dim3(128, 32), blk, 0, stream>>>(f_Wk, fWkT, 2048, 8192);
  transpose_bf16_kernel<<<dim3(32, 128), blk, 0, stream>>>(f_Wv, fWvT, 8192, 2048);

  // 5) chunk-parallel WKV scan + sigmoid(r)*wkv -> S1 (x1 dead)
  wkv_scan_kernel<<<dim3(128), dim3(1024), 0, stream>>>(kbuf, vbuf, rbuf, time_first, time_decay, S1);

  // 6) h1 = h0 + rwkv @ Wo  (in-place on d_out)
  gemm4_kernel<128,3,8,4,EPI_ADDIP><<<gSmall, blk512, 0, stream>>>(
      S1, WoT, out, 2048, 2048, nullptr, 0, 0, 0);

  // 7) fused LN2 + FF mixes: kx2 -> M1, rx2 -> kbuf (x2 never materialized)
  lnmix2_kernel<<<BT_, blk, 0, stream>>>(out, ln2_w, ln2_b, f_tmk, f_tmr, M1, kbuf);

  // 8) r2pre = rx2 @ f_Wr -> vbuf
  gemm4_kernel<128,3,8,4,EPI_BF16><<<gSmall, blk512, 0, stream>>>(
      kbuf, fWrT, vbuf, 2048, 2048, nullptr, 0, 0, 0);

  // 9) FF: kk2 = relu(kx2@f_Wk)^2 -> KK  (256x256 tile, sub-phase pipelined)
  gemm4_kernel<256,2,8,8,EPI_RELU2><<<gRelu, blk512, 0, stream>>>(
      M1, fWkT, KK, 2048, 8192, nullptr, 0, 0, 0);

  // 10) out += sigmoid(r2pre) * (kk2 @ f_Wv)
  gemm4_kernel<128,3,8,4,EPI_SIGADD><<<gSmall, blk512, 0, stream>>>(
      KK, fWvT, out, 8192, 2048, vbuf, 0, 0, 0);
}

// Round 19
// 618.103 us; speedup vs baseline: 1.0412x; 1.0164x over previous
//
#include <hip/hip_runtime.h>

// ---------------- problem constants ----------------
#define B_  2
#define T_  2048
#define H_  2048
#define A_  2048
#define F_  8192
#define BT_ 4096   // B*T rows

typedef __bf16  bf16x8 __attribute__((ext_vector_type(8)));
typedef float   f32x4  __attribute__((ext_vector_type(4)));
typedef short   short8 __attribute__((ext_vector_type(8)));

__device__ __forceinline__ float bf2f(unsigned short b) {
  return __uint_as_float(((unsigned)b) << 16);
}
__device__ __forceinline__ unsigned short f2bf(float f) {
  unsigned u = __float_as_uint(f);
  unsigned r = (u + 0x7FFFu + ((u >> 16) & 1u)) >> 16;   // RNE
  return (unsigned short)r;
}

// global -> LDS direct copy, 16B per lane
typedef __attribute__((address_space(3))) void lds_void_t;
typedef __attribute__((address_space(1))) const void gc_void_t;
__device__ __forceinline__ void gload_lds16(const void* g, void* l) {
  __builtin_amdgcn_global_load_lds((gc_void_t*)g, (lds_void_t*)l, 16, 0, 0);
}

// ---------------- canary: ws too small diagnostic ----------------
__global__ void canary_kernel(float* out) { out[threadIdx.x] = 1000.0f; }

// ---------------- vectorized transpose + fp32->bf16 core (64x64 tile) ----------------
__device__ __forceinline__ void transpose_tile64(
    const float* __restrict__ src, unsigned short* __restrict__ dst,
    int Kd, int Nd, int bx, int by)
{
  __shared__ float tile[64][65];
  const int tx = threadIdx.x & 15;          // 16 col-groups of 4 floats
  const int ty = threadIdx.x >> 4;          // 16 rows per step
  const int n0 = bx * 64;                   // src col base
  const int k0 = by * 64;                   // src row base
#pragma unroll
  for (int i = 0; i < 64; i += 16) {
    float4 v = *(const float4*)(src + (size_t)(k0 + ty + i) * Nd + n0 + tx * 4);
    tile[ty + i][tx*4 + 0] = v.x;
    tile[ty + i][tx*4 + 1] = v.y;
    tile[ty + i][tx*4 + 2] = v.z;
    tile[ty + i][tx*4 + 3] = v.w;
  }
  __syncthreads();
#pragma unroll
  for (int i = 0; i < 64; i += 16) {
    const int r = ty + i;                   // dst-row offset (src col)
    unsigned short o[4];
#pragma unroll
    for (int c = 0; c < 4; ++c) o[c] = f2bf(tile[tx*4 + c][r]);
    *(uint2*)(dst + (size_t)(n0 + r) * Kd + k0 + tx * 4) =
        make_uint2((unsigned)o[0] | ((unsigned)o[1] << 16),
                   (unsigned)o[2] | ((unsigned)o[3] << 16));
  }
}

// z-batched 2048x2048 x5
__global__ __launch_bounds__(256) void transpose5_kernel(
    const float* __restrict__ s0, const float* __restrict__ s1,
    const float* __restrict__ s2, const float* __restrict__ s3,
    const float* __restrict__ s4, unsigned short* __restrict__ dstbase)
{
  const int z = blockIdx.z;
  const float* src = (z == 0) ? s0 : (z == 1) ? s1 : (z == 2) ? s2 : (z == 3) ? s3 : s4;
  unsigned short* dst = dstbase + (size_t)z * 2048 * 2048;
  transpose_tile64(src, dst, 2048, 2048, blockIdx.x, blockIdx.y);
}

// generic
__global__ __launch_bounds__(256) void transpose_bf16_kernel(
    const float* __restrict__ src, unsigned short* __restrict__ dst, int Kd, int Nd)
{
  transpose_tile64(src, dst, Kd, Nd, blockIdx.x, blockIdx.y);
}

// ---------------- block reduction (sum, sumsq) ----------------
__device__ __forceinline__ void block_reduce2(float& a, float& b) {
#pragma unroll
  for (int off = 32; off > 0; off >>= 1) {
    a += __shfl_down(a, off, 64);
    b += __shfl_down(b, off, 64);
  }
  __shared__ float sa[4], sb[4];
  const int lane = threadIdx.x & 63, w = threadIdx.x >> 6;
  __syncthreads();
  if (lane == 0) { sa[w] = a; sb[w] = b; }
  __syncthreads();
  a = sa[0] + sa[1] + sa[2] + sa[3];
  b = sb[0] + sb[1] + sb[2] + sb[3];
}

// ---------------- pre-LN + LN1 fused ----------------
__global__ __launch_bounds__(256) void ln_pre_kernel(
    const float* __restrict__ hidden,
    const float* __restrict__ pw, const float* __restrict__ pb,
    const float* __restrict__ w1, const float* __restrict__ b1,
    float* __restrict__ h0, unsigned short* __restrict__ x1)
{
  const int row = blockIdx.x, tid = threadIdx.x;
  const int c0 = tid * 8;
  const size_t base = (size_t)row * H_ + c0;
  float x[8];
  float4 v0 = *(const float4*)(hidden + base);
  float4 v1 = *(const float4*)(hidden + base + 4);
  x[0]=v0.x; x[1]=v0.y; x[2]=v0.z; x[3]=v0.w;
  x[4]=v1.x; x[5]=v1.y; x[6]=v1.z; x[7]=v1.w;
  float s = 0.f, s2 = 0.f;
#pragma unroll
  for (int j = 0; j < 8; ++j) { s += x[j]; s2 += x[j]*x[j]; }
  block_reduce2(s, s2);
  float mu  = s * (1.f / H_);
  float inv = rsqrtf(fmaxf(s2 * (1.f / H_) - mu*mu, 0.f) + 1e-5f);
  float y[8];
#pragma unroll
  for (int j = 0; j < 8; ++j) y[j] = (x[j] - mu) * inv * pw[c0+j] + pb[c0+j];
  *(float4*)(h0 + base)     = make_float4(y[0],y[1],y[2],y[3]);
  *(float4*)(h0 + base + 4) = make_float4(y[4],y[5],y[6],y[7]);
  s = 0.f; s2 = 0.f;
#pragma unroll
  for (int j = 0; j < 8; ++j) { s += y[j]; s2 += y[j]*y[j]; }
  block_reduce2(s, s2);
  mu  = s * (1.f / H_);
  inv = rsqrtf(fmaxf(s2 * (1.f / H_) - mu*mu, 0.f) + 1e-5f);
  unsigned o[4];
#pragma unroll
  for (int p = 0; p < 4; ++p) {
    unsigned lo = f2bf((y[2*p]   - mu) * inv * w1[c0+2*p]   + b1[c0+2*p]);
    unsigned hi = f2bf((y[2*p+1] - mu) * inv * w1[c0+2*p+1] + b1[c0+2*p+1]);
    o[p] = lo | (hi << 16);
  }
  *(uint4*)(x1 + base) = make_uint4(o[0], o[1], o[2], o[3]);
}

// ---------------- fused LN2 + FF token-shift mixes ----------------
__global__ __launch_bounds__(256) void lnmix2_kernel(
    const float* __restrict__ h1,
    const float* __restrict__ w_, const float* __restrict__ b_,
    const float* __restrict__ tmk_, const float* __restrict__ tmr_,
    unsigned short* __restrict__ kx2b, unsigned short* __restrict__ rx2b)
{
  const int row = blockIdx.x, tid = threadIdx.x;
  const int t = row & (T_ - 1);           // uniform per block
  const int c0 = tid * 8;
  const size_t base = (size_t)row * H_ + c0;
  float x[8], p[8];
  {
    float4 v0 = *(const float4*)(h1 + base);
    float4 v1 = *(const float4*)(h1 + base + 4);
    x[0]=v0.x; x[1]=v0.y; x[2]=v0.z; x[3]=v0.w;
    x[4]=v1.x; x[5]=v1.y; x[6]=v1.z; x[7]=v1.w;
  }
  const bool hasp = (t > 0);
  if (hasp) {
    float4 v0 = *(const float4*)(h1 + base - H_);
    float4 v1 = *(const float4*)(h1 + base - H_ + 4);
    p[0]=v0.x; p[1]=v0.y; p[2]=v0.z; p[3]=v0.w;
    p[4]=v1.x; p[5]=v1.y; p[6]=v1.z; p[7]=v1.w;
  } else {
#pragma unroll
    for (int j = 0; j < 8; ++j) p[j] = 0.f;
  }
  float s = 0.f, s2 = 0.f;
#pragma unroll
  for (int j = 0; j < 8; ++j) { s += x[j]; s2 += x[j]*x[j]; }
  block_reduce2(s, s2);
  const float mu  = s * (1.f / H_);
  const float inv = rsqrtf(fmaxf(s2 * (1.f / H_) - mu*mu, 0.f) + 1e-5f);
  float sp = 0.f, sp2 = 0.f;
#pragma unroll
  for (int j = 0; j < 8; ++j) { sp += p[j]; sp2 += p[j]*p[j]; }
  block_reduce2(sp, sp2);                  // uniform call; unused when !hasp
  const float mup  = sp * (1.f / H_);
  const float invp = rsqrtf(fmaxf(sp2 * (1.f / H_) - mup*mup, 0.f) + 1e-5f);
  unsigned ok[4], orr[4];
#pragma unroll
  for (int q = 0; q < 4; ++q) {
    unsigned ko = 0, ro = 0;
#pragma unroll
    for (int h = 0; h < 2; ++h) {
      const int j = q*2 + h;
      const float xr = (x[j] - mu) * inv * w_[c0+j] + b_[c0+j];
      const float cr = hasp ? (p[j] - mup) * invp * w_[c0+j] + b_[c0+j] : 0.f;
      ko |= (unsigned)f2bf(fmaf(xr - cr, tmk_[c0+j], cr)) << (h*16);
      ro |= (unsigned)f2bf(fmaf(xr - cr, tmr_[c0+j], cr)) << (h*16);
    }
    ok[q] = ko; orr[q] = ro;
  }
  *(uint4*)(kx2b + base) = make_uint4(ok[0],ok[1],ok[2],ok[3]);
  *(uint4*)(rx2b + base) = make_uint4(orr[0],orr[1],orr[2],orr[3]);
}

// ---------------- token-shift + mix (three outputs) ----------------
__global__ __launch_bounds__(256) void mix3_kernel(
    const unsigned short* __restrict__ x,
    const float* __restrict__ mk_, const float* __restrict__ mv_, const float* __restrict__ mr_,
    unsigned short* __restrict__ kx, unsigned short* __restrict__ vx, unsigned short* __restrict__ rx)
{
  const int row = blockIdx.x;
  const int t = row & (T_ - 1);
  const int c0 = threadIdx.x * 8;
  const size_t base = (size_t)row * H_ + c0;
  uint4 xv = *(const uint4*)(x + base);
  uint4 cv = make_uint4(0u,0u,0u,0u);
  if (t > 0) cv = *(const uint4*)(x + base - H_);
  const unsigned xs[4] = {xv.x, xv.y, xv.z, xv.w};
  const unsigned cs[4] = {cv.x, cv.y, cv.z, cv.w};
  unsigned ok[4], ov[4], orr[4];
#pragma unroll
  for (int p = 0; p < 4; ++p) {
    unsigned ko=0, vo=0, ro=0;
#pragma unroll
    for (int h = 0; h < 2; ++h) {
      const int j = p*2 + h;
      float xf = bf2f((unsigned short)((xs[p] >> (h*16)) & 0xFFFFu));
      float cf = bf2f((unsigned short)((cs[p] >> (h*16)) & 0xFFFFu));
      float d  = xf - cf;
      ko |= (unsigned)f2bf(fmaf(d, mk_[c0+j], cf)) << (h*16);
      vo |= (unsigned)f2bf(fmaf(d, mv_[c0+j], cf)) << (h*16);
      ro |= (unsigned)f2bf(fmaf(d, mr_[c0+j], cf)) << (h*16);
    }
    ok[p]=ko; ov[p]=vo; orr[p]=ro;
  }
  *(uint4*)(kx + base) = make_uint4(ok[0],ok[1],ok[2],ok[3]);
  *(uint4*)(vx + base) = make_uint4(ov[0],ov[1],ov[2],ov[3]);
  *(uint4*)(rx + base) = make_uint4(orr[0],orr[1],orr[2],orr[3]);
}

// ---------------- split-K combine: out += sigmoid(sig) * (P0 + P1) ----------------
__global__ __launch_bounds__(256) void sigcombine_kernel(
    const unsigned short* __restrict__ P0, const unsigned short* __restrict__ P1,
    const unsigned short* __restrict__ sigb, float* __restrict__ out)
{
  const size_t i8 = ((size_t)blockIdx.x * 256 + threadIdx.x) * 8;   // 8.4M elems / 8
  uint4 a = *(const uint4*)(P0 + i8);
  uint4 b = *(const uint4*)(P1 + i8);
  uint4 g = *(const uint4*)(sigb + i8);
  float4 o0 = *(const float4*)(out + i8);
  float4 o1 = *(const float4*)(out + i8 + 4);
  float r[8];
  const unsigned aw[4] = {a.x,a.y,a.z,a.w};
  const unsigned bw[4] = {b.x,b.y,b.z,b.w};
  const unsigned gw[4] = {g.x,g.y,g.z,g.w};
#pragma unroll
  for (int p = 0; p < 4; ++p)
#pragma unroll
    for (int h = 0; h < 2; ++h) {
      const float pv = bf2f((unsigned short)((aw[p] >> (h*16)) & 0xFFFFu))
                     + bf2f((unsigned short)((bw[p] >> (h*16)) & 0xFFFFu));
      const float sv = 1.f / (1.f + __expf(-bf2f((unsigned short)((gw[p] >> (h*16)) & 0xFFFFu))));
      r[p*2+h] = sv * pv;
    }
  o0.x += r[0]; o0.y += r[1]; o0.z += r[2]; o0.w += r[3];
  o1.x += r[4]; o1.y += r[5]; o1.z += r[6]; o1.w += r[7];
  *(float4*)(out + i8)     = o0;
  *(float4*)(out + i8 + 4) = o1;
}

// ---------------- chunked-parallel WKV scan ----------------
#define WKV_G 32   // channels per block
#define WKV_C 32   // chunks over T
#define WKV_L 64   // steps per chunk (WKV_C*WKV_L == T_)

__global__ __launch_bounds__(1024) void wkv_scan_kernel(
    const unsigned short* __restrict__ kg, const unsigned short* __restrict__ vg,
    const unsigned short* __restrict__ rg,
    const float* __restrict__ time_first, const float* __restrict__ time_decay,
    unsigned short* __restrict__ rwkv)
{
  const int tid = threadIdx.x;
  const int al  = tid & (WKV_G - 1);        // channel within group
  const int c   = tid >> 5;                 // chunk index 0..31
  const int b   = blockIdx.x >> 6;          // 64 groups per batch
  const int ag  = blockIdx.x & 63;
  const int a   = ag * WKV_G + al;
  const float tf = time_first[a];
  const float w  = -__expf(time_decay[a]);
  const size_t cb = (size_t)b * T_ * A_ + a + (size_t)c * WKV_L * A_;

  // ---- pass 1: per-chunk summary from zero state (k,v only) ----
  float aa = 0.f, bb = 0.f, pp = -1e38f;
  {
    float kb[4], vb[4];
#pragma unroll
    for (int j = 0; j < 4; ++j) {
      kb[j] = bf2f(kg[cb + (size_t)j * A_]);
      vb[j] = bf2f(vg[cb + (size_t)j * A_]);
    }
    for (int t0 = 0; t0 < WKV_L; t0 += 4) {
#pragma unroll
      for (int j = 0; j < 4; ++j) {
        const float kk = kb[j], vv = vb[j];
        const int tn = t0 + j + 4;
        if (tn < WKV_L) {
          kb[j] = bf2f(kg[cb + (size_t)tn * A_]);
          vb[j] = bf2f(vg[cb + (size_t)tn * A_]);
        }
        float ww2 = w + pp;
        float q2  = fmaxf(ww2, kk);
        float e1  = __expf(ww2 - q2);
        float e2  = __expf(kk  - q2);
        aa = e1*aa + e2*vv;
        bb = e1*bb + e2;
        pp = q2;
      }
    }
  }
  __shared__ float saa[WKV_C][WKV_G], sbb[WKV_C][WKV_G], spp[WKV_C][WKV_G];
  saa[c][al] = aa; sbb[c][al] = bb; spp[c][al] = pp;
  __syncthreads();

  // ---- combine: thread i (< WKV_G) walks chunks of channel i ----
  if (tid < WKV_G) {
    float Aa = 0.f, Bb = 0.f, Pp = -1e38f;
    const float Lw = (float)WKV_L * w;
    for (int cc = 0; cc < WKV_C; ++cc) {
      const float na = saa[cc][tid], nb = sbb[cc][tid], np = spp[cc][tid];
      saa[cc][tid] = Aa; sbb[cc][tid] = Bb; spp[cc][tid] = Pp;   // incoming prefix
      const float p1 = Pp + Lw;
      const float pc = fmaxf(p1, np);
      const float f1 = __expf(p1 - pc);
      const float f2 = __expf(np - pc);
      Aa = f1*Aa + f2*na;
      Bb = f1*Bb + f2*nb;
      Pp = pc;
    }
  }
  __syncthreads();
  aa = saa[c][al]; bb = sbb[c][al]; pp = spp[c][al];

  // ---- pass 2: outputs with true prefix state ----
  {
    float kb[4], vb[4], rb[4];
#pragma unroll
    for (int j = 0; j < 4; ++j) {
      kb[j] = bf2f(kg[cb + (size_t)j * A_]);
      vb[j] = bf2f(vg[cb + (size_t)j * A_]);
      rb[j] = bf2f(rg[cb + (size_t)j * A_]);
    }
    for (int t0 = 0; t0 < WKV_L; t0 += 4) {
#pragma unroll
      for (int j = 0; j < 4; ++j) {
        const float kk = kb[j], vv = vb[j], rr = rb[j];
        const int tn = t0 + j + 4;
        if (tn < WKV_L) {
          kb[j] = bf2f(kg[cb + (size_t)tn * A_]);
          vb[j] = bf2f(vg[cb + (size_t)tn * A_]);
          rb[j] = bf2f(rg[cb + (size_t)tn * A_]);
        }
        float ww = tf + kk;
        float q  = fmaxf(pp, ww);
        float e1 = __expf(pp - q);
        float e2 = __expf(ww - q);
        float o  = (e1*aa + e2*vv) / (e1*bb + e2);
        float sr = 1.f / (1.f + __expf(-rr));
        rwkv[cb + (size_t)(t0 + j) * A_] = f2bf(sr * o);
        float ww2 = w + pp;
        float q2  = fmaxf(ww2, kk);
        e1 = __expf(ww2 - q2);
        e2 = __expf(kk  - q2);
        aa = e1*aa + e2*vv;
        bb = e1*bb + e2;
        pp = q2;
      }
    }
  }
}

// ---------------- bf16 GEMM, BK=64, counted-vmcnt + frag-prefetch schedule ----------------
// A [M,lda] bf16 rm (reduction over K <= lda), Bt [N,lda] bf16 rm. BM x 256 tile,
// 512 thr, 8 waves (2M x 4N), per-wave (BM/2) x 64: FM = BM/32, FN = 4. NBUF LDS
// buffers; ONE barrier per K-tile (buffer swap). Counted vmcnt for NBUF=3 (6 loads
// stay in flight); NBUF=2 drains but last stage piece issued ~1 phase before wait.
// Both-sides 8-slot XOR swizzle on 128B rows (rule #21) -> conflict-free reads.
// BM=128 (r13): both kk-halves' 16 ds_reads up front, lgkm(8) -> 16 MFMA -> SP1 ->
// lgkm(0) -> 16 MFMA.  BM=256 (r14): sub-phase pipeline with counted lgkm.
// blockIdx.z batches independent GEMMs / split-K slices: byte strides azB/bzB/czB
// (lda decoupled from K enables split-K: A/B z-offset walks the K axis).
enum { EPI_BF16 = 0, EPI_ADDIP = 1, EPI_RELU2 = 2, EPI_SIGADD = 3 };

template <int BM, int NBUF, int RG, int CG, int EPI>
__global__ __launch_bounds__(512) void gemm4_kernel(
    const unsigned short* __restrict__ Ap, const unsigned short* __restrict__ Bp,
    void* __restrict__ Cp, int K, int Nn,
    const unsigned short* __restrict__ sigb,
    size_t azB, size_t bzB, size_t czB, int lda)
{
  constexpr int BN = 256;
  constexpr int FM = BM / 32;               // fragments per wave in M
  constexpr int FN = 4;
  __shared__ unsigned short As[NBUF * BM * 64];
  __shared__ unsigned short Bs[NBUF * BN * 64];
  const int zz = blockIdx.z;
  Ap = (const unsigned short*)((const char*)Ap + zz * azB);
  Bp = (const unsigned short*)((const char*)Bp + zz * bzB);
  Cp = (void*)((char*)Cp + zz * czB);
  const int tid  = threadIdx.x;
  const int lane = tid & 63;
  const int lr = lane & 15;
  const int hi = lane >> 4;                 // 0..3, selects 8-elem k-piece
  const int rx7 = lr & 7;                   // row&7 for fragment rows
  const int wid = tid >> 6;
  const int wm = wid >> 2, wn = wid & 3;    // 2M x 4N
  const int rowW = wm * (BM / 2);
  const int colW = wn * 64;
  // region-based XCD mapping (row-fastest within region)
  const int gx = gridDim.x;                 // col-tiles
  const int gy = gridDim.y;                 // row-tiles
  const int flat = blockIdx.y * gx + blockIdx.x;
  const int xcd = flat & 7;
  const int j = flat >> 3;                  // 0 .. RG*CG-1
  const int rgc = gy / RG;                  // row-group count (rgc * cgc == 8)
  const int r_idx = xcd % rgc;
  const int c_idx = xcd / rgc;
  const int row_l = j % RG;
  const int col_l = j / RG;
  const long row0 = (long)(r_idx * RG + row_l) * BM;
  const long col0 = (long)(c_idx * CG + col_l) * BN;
  const unsigned short* Ab = Ap + (size_t)row0 * lda;
  const unsigned short* Bb = Bp + (size_t)col0 * lda;
  const int srow8 = tid >> 3;               // 0..63
  const int sslot = (tid & 7) ^ (srow8 & 7);// permuted global source slot
  f32x4 acc[FM][FN] = {};

  // stage pieces:
  //  BM=128: SP0 = {A0, A1, B0} (3 loads), SP1 = {B1, B2, B3} (3 loads), 6/K-tile
  //  BM=256: SPq q=0..3: {A0A1},{A2A3},{B0B1},{B2B3} (2 loads each), 8/K-tile
  auto SP0 = [&](int bufi, int tt) {
    unsigned short* asb = As + bufi * (BM * 64);
    unsigned short* bsb = Bs + bufi * (BN * 64);
    const size_t ko = (size_t)tt * 64 + sslot * 8;
    gload_lds16(Ab + (size_t)srow8        * lda + ko, asb + tid * 8);
    gload_lds16(Ab + (size_t)(srow8 + 64) * lda + ko, asb + 4096 + tid * 8);
    gload_lds16(Bb + (size_t)srow8        * lda + ko, bsb + tid * 8);
  };
  auto SP1 = [&](int bufi, int tt) {
    unsigned short* bsb = Bs + bufi * (BN * 64);
    const size_t ko = (size_t)tt * 64 + sslot * 8;
    gload_lds16(Bb + (size_t)(srow8 + 64)  * lda + ko, bsb + 4096  + tid * 8);
    gload_lds16(Bb + (size_t)(srow8 + 128) * lda + ko, bsb + 8192  + tid * 8);
    gload_lds16(Bb + (size_t)(srow8 + 192) * lda + ko, bsb + 12288 + tid * 8);
  };
  auto SPq = [&](int bufi, int tt, int q) {
    const size_t ko = (size_t)tt * 64 + sslot * 8;
    if (q < 2) {
      unsigned short* asb = As + bufi * (BM * 64);
      gload_lds16(Ab + (size_t)(srow8 + q*128)      * lda + ko, asb + q*8192 + tid * 8);
      gload_lds16(Ab + (size_t)(srow8 + q*128 + 64) * lda + ko, asb + q*8192 + 4096 + tid * 8);
    } else {
      const int qq = q - 2;
      unsigned short* bsb = Bs + bufi * (BN * 64);
      gload_lds16(Bb + (size_t)(srow8 + qq*128)      * lda + ko, bsb + qq*8192 + tid * 8);
      gload_lds16(Bb + (size_t)(srow8 + qq*128 + 64) * lda + ko, bsb + qq*8192 + 4096 + tid * 8);
    }
  };

  const int nt = K >> 6;                    // K-tiles of 64
  if constexpr (BM == 128) {
    SP0(0, 0); SP1(0, 0);
    if constexpr (NBUF == 3) { SP0(1, 1); SP1(1, 1); }
  } else {
#pragma unroll
    for (int q = 0; q < 4; ++q) SPq(0, 0, q);
  }
  int cur = 0;
  for (int t = 0; t < nt; ++t) {
    if constexpr (NBUF == 3) {
      if (t + 1 < nt) asm volatile("s_waitcnt vmcnt(6)" ::: "memory");
      else            asm volatile("s_waitcnt vmcnt(0)" ::: "memory");
    } else {
      asm volatile("s_waitcnt vmcnt(0)" ::: "memory");
    }
    __builtin_amdgcn_s_barrier();           // ONLY barrier per K-tile (buffer swap)
    int nb = cur + (NBUF - 1); if (nb >= NBUF) nb -= NBUF;
    const unsigned short* asb = As + cur * (BM * 64);
    const unsigned short* bsb = Bs + cur * (BN * 64);
    if constexpr (BM == 128) {
      // r13 frag prefetch: issue BOTH kk-halves' reads, counted lgkm waits
      bf16x8 af0[4], bf0[4], af1[4], bf1[4];
      const int p0 = (0*4 + hi) ^ rx7;
      const int p1 = (1*4 + hi) ^ rx7;
#pragma unroll
      for (int m = 0; m < 4; ++m)
        af0[m] = __builtin_bit_cast(bf16x8,
            *(const short8*)(asb + (rowW + m*16 + lr) * 64 + p0*8));
#pragma unroll
      for (int n = 0; n < 4; ++n)
        bf0[n] = __builtin_bit_cast(bf16x8,
            *(const short8*)(bsb + (colW + n*16 + lr) * 64 + p0*8));
#pragma unroll
      for (int m = 0; m < 4; ++m)
        af1[m] = __builtin_bit_cast(bf16x8,
            *(const short8*)(asb + (rowW + m*16 + lr) * 64 + p1*8));
#pragma unroll
      for (int n = 0; n < 4; ++n)
        bf1[n] = __builtin_bit_cast(bf16x8,
            *(const short8*)(bsb + (colW + n*16 + lr) * 64 + p1*8));
      if (t + NBUF - 1 < nt) SP0(nb, t + NBUF - 1);
      asm volatile("s_waitcnt lgkmcnt(8)" ::: "memory");   // kk0's 8 reads done
      __builtin_amdgcn_sched_barrier(0);
      __builtin_amdgcn_s_setprio(1);
#pragma unroll
      for (int m = 0; m < 4; ++m)
#pragma unroll
        for (int n = 0; n < 4; ++n)
          acc[m][n] = __builtin_amdgcn_mfma_f32_16x16x32_bf16(af0[m], bf0[n], acc[m][n], 0, 0, 0);
      __builtin_amdgcn_s_setprio(0);
      if (t + NBUF - 1 < nt) SP1(nb, t + NBUF - 1);
      asm volatile("s_waitcnt lgkmcnt(0)" ::: "memory");   // kk1's reads done
      __builtin_amdgcn_sched_barrier(0);
      __builtin_amdgcn_s_setprio(1);
#pragma unroll
      for (int m = 0; m < 4; ++m)
#pragma unroll
        for (int n = 0; n < 4; ++n)
          acc[m][n] = __builtin_amdgcn_mfma_f32_16x16x32_bf16(af1[m], bf1[n], acc[m][n], 0, 0, 0);
      __builtin_amdgcn_s_setprio(0);
    } else {
      // sub-phase pipeline (r14): subs = (kk0,mh0),(kk0,mh1),(kk1,mh0),(kk1,mh1)
      bf16x8 aF[2][4], bF[2][4];
      const int p0 = (0*4 + hi) ^ rx7;
      const int p1 = (1*4 + hi) ^ rx7;
#pragma unroll
      for (int n = 0; n < 4; ++n)
        bF[0][n] = __builtin_bit_cast(bf16x8,
            *(const short8*)(bsb + (colW + n*16 + lr) * 64 + p0*8));
#pragma unroll
      for (int m = 0; m < 4; ++m)
        aF[0][m] = __builtin_bit_cast(bf16x8,
            *(const short8*)(asb + (rowW + m*16 + lr) * 64 + p0*8));
#pragma unroll
      for (int m = 0; m < 4; ++m)
        aF[1][m] = __builtin_bit_cast(bf16x8,
            *(const short8*)(asb + (rowW + (4+m)*16 + lr) * 64 + p0*8));
      if (t + 1 < nt) SPq(nb, t + 1, 0);
      asm volatile("s_waitcnt lgkmcnt(4)" ::: "memory");
      __builtin_amdgcn_sched_barrier(0);
      __builtin_amdgcn_s_setprio(1);
#pragma unroll
      for (int m = 0; m < 4; ++m)
#pragma unroll
        for (int n = 0; n < 4; ++n)
          acc[m][n] = __builtin_amdgcn_mfma_f32_16x16x32_bf16(aF[0][m], bF[0][n], acc[m][n], 0, 0, 0);
      __builtin_amdgcn_s_setprio(0);
#pragma unroll
      for (int n = 0; n < 4; ++n)
        bF[1][n] = __builtin_bit_cast(bf16x8,
            *(const short8*)(bsb + (colW + n*16 + lr) * 64 + p1*8));
#pragma unroll
      for (int m = 0; m < 4; ++m)
        aF[0][m] = __builtin_bit_cast(bf16x8,
            *(const short8*)(asb + (rowW + m*16 + lr) * 64 + p1*8));
      if (t + 1 < nt) SPq(nb, t + 1, 1);
      asm volatile("s_waitcnt lgkmcnt(8)" ::: "memory");
      __builtin_amdgcn_sched_barrier(0);
      __builtin_amdgcn_s_setprio(1);
#pragma unroll
      for (int m = 0; m < 4; ++m)
#pragma unroll
        for (int n = 0; n < 4; ++n)
          acc[4+m][n] = __builtin_amdgcn_mfma_f32_16x16x32_bf16(aF[1][m], bF[0][n], acc[4+m][n], 0, 0, 0);
      __builtin_amdgcn_s_setprio(0);
#pragma unroll
      for (int m = 0; m < 4; ++m)
        aF[1][m] = __builtin_bit_cast(bf16x8,
            *(const short8*)(asb + (rowW + (4+m)*16 + lr) * 64 + p1*8));
      if (t + 1 < nt) SPq(nb, t + 1, 2);
      asm volatile("s_waitcnt lgkmcnt(4)" ::: "memory");
      __builtin_amdgcn_sched_barrier(0);
      __builtin_amdgcn_s_setprio(1);
#pragma unroll
      for (int m = 0; m < 4; ++m)
#pragma unroll
        for (int n = 0; n < 4; ++n)
          acc[m][n] = __builtin_amdgcn_mfma_f32_16x16x32_bf16(aF[0][m], bF[1][n], acc[m][n], 0, 0, 0);
      __builtin_amdgcn_s_setprio(0);
      if (t + 1 < nt) SPq(nb, t + 1, 3);
      asm volatile("s_waitcnt lgkmcnt(0)" ::: "memory");
      __builtin_amdgcn_sched_barrier(0);
      __builtin_amdgcn_s_setprio(1);
#pragma unroll
      for (int m = 0; m < 4; ++m)
#pragma unroll
        for (int n = 0; n < 4; ++n)
          acc[4+m][n] = __builtin_amdgcn_mfma_f32_16x16x32_bf16(aF[1][m], bF[1][n], acc[4+m][n], 0, 0, 0);
      __builtin_amdgcn_s_setprio(0);
    }
    cur = (cur + 1 == NBUF) ? 0 : cur + 1;
  }

  // C/D layout: col = lane&15, row = (lane>>4)*4 + j
#pragma unroll
  for (int m = 0; m < FM; ++m) {
#pragma unroll
    for (int n = 0; n < FN; ++n) {
      const long col = col0 + colW + n*16 + lr;
#pragma unroll
      for (int j2 = 0; j2 < 4; ++j2) {
        const long row = row0 + rowW + m*16 + hi*4 + j2;
        const size_t idx = (size_t)row * Nn + col;
        const float v = acc[m][n][j2];
        if (EPI == EPI_BF16) {
          ((unsigned short*)Cp)[idx] = f2bf(v);
        } else if (EPI == EPI_ADDIP) {
          float* C = (float*)Cp;
          C[idx] = C[idx] + v;                       // in-place residual add
        } else if (EPI == EPI_RELU2) {
          float rr = v > 0.f ? v : 0.f;
          ((unsigned short*)Cp)[idx] = f2bf(rr * rr);
        } else {                                     // EPI_SIGADD
          float s = 1.f / (1.f + __expf(-bf2f(sigb[idx])));
          float* C = (float*)Cp;
          C[idx] = C[idx] + s * v;
        }
      }
    }
  }
}

// ---------------- workspace layout (MB) ----------------
// 0..48   mix3 outputs kx/vx/rx (16MB each)  -> later fWkT@0..32, fWvT@32..64
// 64..72  WkT   72..80 WvT   80..88 WrT   88..96 WoT   96..104 fWrT
// 104..120 S1 (x1 -> rwkv)
// 120..136 kbuf (k -> rx2)  136..152 vbuf (v -> r2pre)  152..184 PK (split-K partials,
//   aliases rbuf(152..168)=r and M1(168..184)=kx2, both dead by split-K time)
// KK (kk2 [4096,8192] bf16, 64MB) aliases 64..128, all dead by the FF GEMMs.
#define MB(x) ((size_t)(x) << 20)
#define WS_NEED MB(184)

extern "C" void kernel_launch(void* const* d_in, const int* in_sizes, int n_in,
                              void* d_out, int out_size, void* d_ws, size_t ws_size,
                              hipStream_t stream) {
  const float* hidden     = (const float*)d_in[0];
  const float* pre_w      = (const float*)d_in[1];
  const float* pre_b      = (const float*)d_in[2];
  const float* ln1_w      = (const float*)d_in[3];
  const float* ln1_b      = (const float*)d_in[4];
  const float* ln2_w      = (const float*)d_in[5];
  const float* ln2_b      = (const float*)d_in[6];
  const float* time_decay = (const float*)d_in[7];
  const float* time_first = (const float*)d_in[8];
  const float* tmk        = (const float*)d_in[9];
  const float* tmv        = (const float*)d_in[10];
  const float* tmr        = (const float*)d_in[11];
  const float* Wk         = (const float*)d_in[12];
  const float* Wv         = (const float*)d_in[13];
  const float* Wr         = (const float*)d_in[14];
  const float* Wo         = (const float*)d_in[15];
  const float* f_tmk      = (const float*)d_in[16];
  const float* f_tmr      = (const float*)d_in[17];
  const float* f_Wk       = (const float*)d_in[18];
  const float* f_Wr       = (const float*)d_in[19];
  const float* f_Wv       = (const float*)d_in[20];
  float* out = (float*)d_out;
  char*  ws  = (char*)d_ws;

  if (ws_size < WS_NEED) {               // diagnostic canary: absmax ~1000 => ws too small
    canary_kernel<<<1, 256, 0, stream>>>(out);
    return;
  }

  unsigned short* MX   = (unsigned short*)(ws + MB(0));    // kx/vx/rx (3 x 16MB)
  unsigned short* fWkT = (unsigned short*)(ws + MB(0));    // after mixes dead
  unsigned short* fWvT = (unsigned short*)(ws + MB(32));
  unsigned short* WkT  = (unsigned short*)(ws + MB(64));   // Wk/Wv/Wr contiguous for z-stride
  unsigned short* WoT  = (unsigned short*)(ws + MB(88));
  unsigned short* fWrT = (unsigned short*)(ws + MB(96));
  unsigned short* KK   = (unsigned short*)(ws + MB(64));   // kk2 full, aliases dead data
  unsigned short* S1   = (unsigned short*)(ws + MB(104));  // x1 -> rwkv
  unsigned short* kbuf = (unsigned short*)(ws + MB(120));  // k -> rx2
  unsigned short* vbuf = (unsigned short*)(ws + MB(136));  // v -> r2pre
  unsigned short* rbuf = (unsigned short*)(ws + MB(152));  // r
  unsigned short* M1   = (unsigned short*)(ws + MB(168));  // kx2
  unsigned short* PK   = (unsigned short*)(ws + MB(152));  // split-K partials (2x16MB)

  const dim3 blk(256);
  const dim3 blk512(512);
  const dim3 gSmall(8, 32);      // 128x256 tile over [4096,2048] -> 256 blocks
  const dim3 gSmall3(8, 32, 3);  // 3 batched projections (BM=128)
  const dim3 gBig2(8, 16, 2);    // 256x256 tile, split-K=2 -> 256 blocks
  const dim3 gRelu(32, 16);      // 256x256 tile over [4096,8192] -> 512 blocks

  // 1) five small weight transposes in ONE z=5 dispatch (vectorized 64x64 tiles)
  transpose5_kernel<<<dim3(32, 32, 5), blk, 0, stream>>>(Wk, Wv, Wr, Wo, f_Wr, WkT);

  // 2) pre-LN + LN1: h0 -> d_out (fp32), x1 -> S1 (bf16)
  ln_pre_kernel<<<BT_, blk, 0, stream>>>(hidden, pre_w, pre_b, ln1_w, ln1_b, out, S1);

  // 3) one mix pass (kx/vx/rx) + one batched z=3 GEMM: {k,v,r} = mix @ {Wk,Wv,Wr}^T
  mix3_kernel<<<BT_, blk, 0, stream>>>(S1, tmk, tmv, tmr, MX, MX + (MB(16)>>1), MX + (MB(32)>>1));
  gemm4_kernel<128,3,8,4,EPI_BF16><<<gSmall3, blk512, 0, stream>>>(
      MX, WkT, kbuf, 2048, 2048, nullptr, MB(16), MB(8), MB(16), 2048);

  // 4) deferred big transposes (mix buffers now dead), vectorized
  transpose_bf16_kernel<<<dim3(128, 32), blk, 0, stream>>>(f_Wk, fWkT, 2048, 8192);
  transpose_bf16_kernel<<<dim3(32, 128), blk, 0, stream>>>(f_Wv, fWvT, 8192, 2048);

  // 5) chunk-parallel WKV scan + sigmoid(r)*wkv -> S1 (x1 dead)
  wkv_scan_kernel<<<dim3(128), dim3(1024), 0, stream>>>(kbuf, vbuf, rbuf, time_first, time_decay, S1);

  // 6) h1 = h0 + rwkv @ Wo  (in-place on d_out)
  gemm4_kernel<128,3,8,4,EPI_ADDIP><<<gSmall, blk512, 0, stream>>>(
      S1, WoT, out, 2048, 2048, nullptr, 0, 0, 0, 2048);

  // 7) fused LN2 + FF mixes: kx2 -> M1, rx2 -> kbuf (x2 never materialized)
  lnmix2_kernel<<<BT_, blk, 0, stream>>>(out, ln2_w, ln2_b, f_tmk, f_tmr, M1, kbuf);

  // 8) r2pre = rx2 @ f_Wr -> vbuf
  gemm4_kernel<128,3,8,4,EPI_BF16><<<gSmall, blk512, 0, stream>>>(
      kbuf, fWrT, vbuf, 2048, 2048, nullptr, 0, 0, 0, 2048);

  // 9) FF: kk2 = relu(kx2@f_Wk)^2 -> KK  (256x256 tile, sub-phase pipelined)
  gemm4_kernel<256,2,8,8,EPI_RELU2><<<gRelu, blk512, 0, stream>>>(
      M1, fWkT, KK, 2048, 8192, nullptr, 0, 0, 0, 2048);

  // 10) split-K=2 (BM=256, full machine): P{0,1} = kk2[:, z*4096:] @ f_WvT -> PK bf16
  //     (rbuf/M1 dead by now; z walks the K axis via azB/bzB; lda=8192)
  gemm4_kernel<256,2,8,2,EPI_BF16><<<gBig2, blk512, 0, stream>>>(
      KK, fWvT, PK, 4096, 2048, nullptr, (size_t)4096*2, (size_t)4096*2, MB(16), 8192);

  // 11) out += sigmoid(r2pre) * (P0 + P1)
  sigcombine_kernel<<<dim3(4096), blk, 0, stream>>>(PK, PK + (MB(16)>>1), vbuf, out);
}

// Round 20
// 612.368 us; speedup vs baseline: 1.0510x; 1.0094x over previous
//
#include <hip/hip_runtime.h>

// ---------------- problem constants ----------------
#define B_  2
#define T_  2048
#define H_  2048
#define A_  2048
#define F_  8192
#define BT_ 4096   // B*T rows

typedef __bf16  bf16x8 __attribute__((ext_vector_type(8)));
typedef float   f32x4  __attribute__((ext_vector_type(4)));
typedef short   short8 __attribute__((ext_vector_type(8)));

__device__ __forceinline__ float bf2f(unsigned short b) {
  return __uint_as_float(((unsigned)b) << 16);
}
__device__ __forceinline__ unsigned short f2bf(float f) {
  unsigned u = __float_as_uint(f);
  unsigned r = (u + 0x7FFFu + ((u >> 16) & 1u)) >> 16;   // RNE
  return (unsigned short)r;
}

// global -> LDS direct copy, 16B per lane
typedef __attribute__((address_space(3))) void lds_void_t;
typedef __attribute__((address_space(1))) const void gc_void_t;
__device__ __forceinline__ void gload_lds16(const void* g, void* l) {
  __builtin_amdgcn_global_load_lds((gc_void_t*)g, (lds_void_t*)l, 16, 0, 0);
}

// ---------------- canary: ws too small diagnostic ----------------
__global__ void canary_kernel(float* out) { out[threadIdx.x] = 1000.0f; }

// ---------------- vectorized transpose + fp32->bf16 core (64x64 tile) ----------------
__device__ __forceinline__ void transpose_tile64(
    const float* __restrict__ src, unsigned short* __restrict__ dst,
    int Kd, int Nd, int bx, int by)
{
  __shared__ float tile[64][65];
  const int tx = threadIdx.x & 15;          // 16 col-groups of 4 floats
  const int ty = threadIdx.x >> 4;          // 16 rows per step
  const int n0 = bx * 64;                   // src col base
  const int k0 = by * 64;                   // src row base
#pragma unroll
  for (int i = 0; i < 64; i += 16) {
    float4 v = *(const float4*)(src + (size_t)(k0 + ty + i) * Nd + n0 + tx * 4);
    tile[ty + i][tx*4 + 0] = v.x;
    tile[ty + i][tx*4 + 1] = v.y;
    tile[ty + i][tx*4 + 2] = v.z;
    tile[ty + i][tx*4 + 3] = v.w;
  }
  __syncthreads();
#pragma unroll
  for (int i = 0; i < 64; i += 16) {
    const int r = ty + i;                   // dst-row offset (src col)
    unsigned short o[4];
#pragma unroll
    for (int c = 0; c < 4; ++c) o[c] = f2bf(tile[tx*4 + c][r]);
    *(uint2*)(dst + (size_t)(n0 + r) * Kd + k0 + tx * 4) =
        make_uint2((unsigned)o[0] | ((unsigned)o[1] << 16),
                   (unsigned)o[2] | ((unsigned)o[3] << 16));
  }
}

// z-batched 2048x2048 x5
__global__ __launch_bounds__(256) void transpose5_kernel(
    const float* __restrict__ s0, const float* __restrict__ s1,
    const float* __restrict__ s2, const float* __restrict__ s3,
    const float* __restrict__ s4, unsigned short* __restrict__ dstbase)
{
  const int z = blockIdx.z;
  const float* src = (z == 0) ? s0 : (z == 1) ? s1 : (z == 2) ? s2 : (z == 3) ? s3 : s4;
  unsigned short* dst = dstbase + (size_t)z * 2048 * 2048;
  transpose_tile64(src, dst, 2048, 2048, blockIdx.x, blockIdx.y);
}

// generic
__global__ __launch_bounds__(256) void transpose_bf16_kernel(
    const float* __restrict__ src, unsigned short* __restrict__ dst, int Kd, int Nd)
{
  transpose_tile64(src, dst, Kd, Nd, blockIdx.x, blockIdx.y);
}

// ---------------- block reduction (sum, sumsq) ----------------
__device__ __forceinline__ void block_reduce2(float& a, float& b) {
#pragma unroll
  for (int off = 32; off > 0; off >>= 1) {
    a += __shfl_down(a, off, 64);
    b += __shfl_down(b, off, 64);
  }
  __shared__ float sa[4], sb[4];
  const int lane = threadIdx.x & 63, w = threadIdx.x >> 6;
  __syncthreads();
  if (lane == 0) { sa[w] = a; sb[w] = b; }
  __syncthreads();
  a = sa[0] + sa[1] + sa[2] + sa[3];
  b = sb[0] + sb[1] + sb[2] + sb[3];
}

// ---------------- pre-LN + LN1 fused ----------------
__global__ __launch_bounds__(256) void ln_pre_kernel(
    const float* __restrict__ hidden,
    const float* __restrict__ pw, const float* __restrict__ pb,
    const float* __restrict__ w1, const float* __restrict__ b1,
    float* __restrict__ h0, unsigned short* __restrict__ x1)
{
  const int row = blockIdx.x, tid = threadIdx.x;
  const int c0 = tid * 8;
  const size_t base = (size_t)row * H_ + c0;
  float x[8];
  float4 v0 = *(const float4*)(hidden + base);
  float4 v1 = *(const float4*)(hidden + base + 4);
  x[0]=v0.x; x[1]=v0.y; x[2]=v0.z; x[3]=v0.w;
  x[4]=v1.x; x[5]=v1.y; x[6]=v1.z; x[7]=v1.w;
  float s = 0.f, s2 = 0.f;
#pragma unroll
  for (int j = 0; j < 8; ++j) { s += x[j]; s2 += x[j]*x[j]; }
  block_reduce2(s, s2);
  float mu  = s * (1.f / H_);
  float inv = rsqrtf(fmaxf(s2 * (1.f / H_) - mu*mu, 0.f) + 1e-5f);
  float y[8];
#pragma unroll
  for (int j = 0; j < 8; ++j) y[j] = (x[j] - mu) * inv * pw[c0+j] + pb[c0+j];
  *(float4*)(h0 + base)     = make_float4(y[0],y[1],y[2],y[3]);
  *(float4*)(h0 + base + 4) = make_float4(y[4],y[5],y[6],y[7]);
  s = 0.f; s2 = 0.f;
#pragma unroll
  for (int j = 0; j < 8; ++j) { s += y[j]; s2 += y[j]*y[j]; }
  block_reduce2(s, s2);
  mu  = s * (1.f / H_);
  inv = rsqrtf(fmaxf(s2 * (1.f / H_) - mu*mu, 0.f) + 1e-5f);
  unsigned o[4];
#pragma unroll
  for (int p = 0; p < 4; ++p) {
    unsigned lo = f2bf((y[2*p]   - mu) * inv * w1[c0+2*p]   + b1[c0+2*p]);
    unsigned hi = f2bf((y[2*p+1] - mu) * inv * w1[c0+2*p+1] + b1[c0+2*p+1]);
    o[p] = lo | (hi << 16);
  }
  *(uint4*)(x1 + base) = make_uint4(o[0], o[1], o[2], o[3]);
}

// ---------------- fused LN2 + FF token-shift mixes ----------------
__global__ __launch_bounds__(256) void lnmix2_kernel(
    const float* __restrict__ h1,
    const float* __restrict__ w_, const float* __restrict__ b_,
    const float* __restrict__ tmk_, const float* __restrict__ tmr_,
    unsigned short* __restrict__ kx2b, unsigned short* __restrict__ rx2b)
{
  const int row = blockIdx.x, tid = threadIdx.x;
  const int t = row & (T_ - 1);           // uniform per block
  const int c0 = tid * 8;
  const size_t base = (size_t)row * H_ + c0;
  float x[8], p[8];
  {
    float4 v0 = *(const float4*)(h1 + base);
    float4 v1 = *(const float4*)(h1 + base + 4);
    x[0]=v0.x; x[1]=v0.y; x[2]=v0.z; x[3]=v0.w;
    x[4]=v1.x; x[5]=v1.y; x[6]=v1.z; x[7]=v1.w;
  }
  const bool hasp = (t > 0);
  if (hasp) {
    float4 v0 = *(const float4*)(h1 + base - H_);
    float4 v1 = *(const float4*)(h1 + base - H_ + 4);
    p[0]=v0.x; p[1]=v0.y; p[2]=v0.z; p[3]=v0.w;
    p[4]=v1.x; p[5]=v1.y; p[6]=v1.z; p[7]=v1.w;
  } else {
#pragma unroll
    for (int j = 0; j < 8; ++j) p[j] = 0.f;
  }
  float s = 0.f, s2 = 0.f;
#pragma unroll
  for (int j = 0; j < 8; ++j) { s += x[j]; s2 += x[j]*x[j]; }
  block_reduce2(s, s2);
  const float mu  = s * (1.f / H_);
  const float inv = rsqrtf(fmaxf(s2 * (1.f / H_) - mu*mu, 0.f) + 1e-5f);
  float sp = 0.f, sp2 = 0.f;
#pragma unroll
  for (int j = 0; j < 8; ++j) { sp += p[j]; sp2 += p[j]*p[j]; }
  block_reduce2(sp, sp2);                  // uniform call; unused when !hasp
  const float mup  = sp * (1.f / H_);
  const float invp = rsqrtf(fmaxf(sp2 * (1.f / H_) - mup*mup, 0.f) + 1e-5f);
  unsigned ok[4], orr[4];
#pragma unroll
  for (int q = 0; q < 4; ++q) {
    unsigned ko = 0, ro = 0;
#pragma unroll
    for (int h = 0; h < 2; ++h) {
      const int j = q*2 + h;
      const float xr = (x[j] - mu) * inv * w_[c0+j] + b_[c0+j];
      const float cr = hasp ? (p[j] - mup) * invp * w_[c0+j] + b_[c0+j] : 0.f;
      ko |= (unsigned)f2bf(fmaf(xr - cr, tmk_[c0+j], cr)) << (h*16);
      ro |= (unsigned)f2bf(fmaf(xr - cr, tmr_[c0+j], cr)) << (h*16);
    }
    ok[q] = ko; orr[q] = ro;
  }
  *(uint4*)(kx2b + base) = make_uint4(ok[0],ok[1],ok[2],ok[3]);
  *(uint4*)(rx2b + base) = make_uint4(orr[0],orr[1],orr[2],orr[3]);
}

// ---------------- token-shift + mix (three outputs) ----------------
__global__ __launch_bounds__(256) void mix3_kernel(
    const unsigned short* __restrict__ x,
    const float* __restrict__ mk_, const float* __restrict__ mv_, const float* __restrict__ mr_,
    unsigned short* __restrict__ kx, unsigned short* __restrict__ vx, unsigned short* __restrict__ rx)
{
  const int row = blockIdx.x;
  const int t = row & (T_ - 1);
  const int c0 = threadIdx.x * 8;
  const size_t base = (size_t)row * H_ + c0;
  uint4 xv = *(const uint4*)(x + base);
  uint4 cv = make_uint4(0u,0u,0u,0u);
  if (t > 0) cv = *(const uint4*)(x + base - H_);
  const unsigned xs[4] = {xv.x, xv.y, xv.z, xv.w};
  const unsigned cs[4] = {cv.x, cv.y, cv.z, cv.w};
  unsigned ok[4], ov[4], orr[4];
#pragma unroll
  for (int p = 0; p < 4; ++p) {
    unsigned ko=0, vo=0, ro=0;
#pragma unroll
    for (int h = 0; h < 2; ++h) {
      const int j = p*2 + h;
      float xf = bf2f((unsigned short)((xs[p] >> (h*16)) & 0xFFFFu));
      float cf = bf2f((unsigned short)((cs[p] >> (h*16)) & 0xFFFFu));
      float d  = xf - cf;
      ko |= (unsigned)f2bf(fmaf(d, mk_[c0+j], cf)) << (h*16);
      vo |= (unsigned)f2bf(fmaf(d, mv_[c0+j], cf)) << (h*16);
      ro |= (unsigned)f2bf(fmaf(d, mr_[c0+j], cf)) << (h*16);
    }
    ok[p]=ko; ov[p]=vo; orr[p]=ro;
  }
  *(uint4*)(kx + base) = make_uint4(ok[0],ok[1],ok[2],ok[3]);
  *(uint4*)(vx + base) = make_uint4(ov[0],ov[1],ov[2],ov[3]);
  *(uint4*)(rx + base) = make_uint4(orr[0],orr[1],orr[2],orr[3]);
}

// ---------------- split-K combine: out += sigmoid(sig) * (P0 + P1) ----------------
__global__ __launch_bounds__(256) void sigcombine_kernel(
    const unsigned short* __restrict__ P0, const unsigned short* __restrict__ P1,
    const unsigned short* __restrict__ sigb, float* __restrict__ out)
{
  const size_t i8 = ((size_t)blockIdx.x * 256 + threadIdx.x) * 8;   // 8.4M elems / 8
  uint4 a = *(const uint4*)(P0 + i8);
  uint4 b = *(const uint4*)(P1 + i8);
  uint4 g = *(const uint4*)(sigb + i8);
  float4 o0 = *(const float4*)(out + i8);
  float4 o1 = *(const float4*)(out + i8 + 4);
  float r[8];
  const unsigned aw[4] = {a.x,a.y,a.z,a.w};
  const unsigned bw[4] = {b.x,b.y,b.z,b.w};
  const unsigned gw[4] = {g.x,g.y,g.z,g.w};
#pragma unroll
  for (int p = 0; p < 4; ++p)
#pragma unroll
    for (int h = 0; h < 2; ++h) {
      const float pv = bf2f((unsigned short)((aw[p] >> (h*16)) & 0xFFFFu))
                     + bf2f((unsigned short)((bw[p] >> (h*16)) & 0xFFFFu));
      const float sv = 1.f / (1.f + __expf(-bf2f((unsigned short)((gw[p] >> (h*16)) & 0xFFFFu))));
      r[p*2+h] = sv * pv;
    }
  o0.x += r[0]; o0.y += r[1]; o0.z += r[2]; o0.w += r[3];
  o1.x += r[4]; o1.y += r[5]; o1.z += r[6]; o1.w += r[7];
  *(float4*)(out + i8)     = o0;
  *(float4*)(out + i8 + 4) = o1;
}

// ---------------- chunked-parallel WKV scan (r20: 2x TLP, half serial depth) ----------------
#define WKV_G 16   // channels per block
#define WKV_C 64   // chunks over T
#define WKV_L 32   // steps per chunk (WKV_C*WKV_L == T_)

__global__ __launch_bounds__(1024) void wkv_scan_kernel(
    const unsigned short* __restrict__ kg, const unsigned short* __restrict__ vg,
    const unsigned short* __restrict__ rg,
    const float* __restrict__ time_first, const float* __restrict__ time_decay,
    unsigned short* __restrict__ rwkv)
{
  const int tid = threadIdx.x;
  const int al  = tid & (WKV_G - 1);        // channel within group
  const int c   = tid >> 4;                 // chunk index 0..63
  const int b   = blockIdx.x >> 7;          // 128 groups per batch
  const int ag  = blockIdx.x & 127;
  const int a   = ag * WKV_G + al;
  const float tf = time_first[a];
  const float w  = -__expf(time_decay[a]);
  const size_t cb = (size_t)b * T_ * A_ + a + (size_t)c * WKV_L * A_;

  // ---- pass 1: per-chunk summary from zero state (k,v only) ----
  float aa = 0.f, bb = 0.f, pp = -1e38f;
  {
    float kb[4], vb[4];
#pragma unroll
    for (int j = 0; j < 4; ++j) {
      kb[j] = bf2f(kg[cb + (size_t)j * A_]);
      vb[j] = bf2f(vg[cb + (size_t)j * A_]);
    }
    for (int t0 = 0; t0 < WKV_L; t0 += 4) {
#pragma unroll
      for (int j = 0; j < 4; ++j) {
        const float kk = kb[j], vv = vb[j];
        const int tn = t0 + j + 4;
        if (tn < WKV_L) {
          kb[j] = bf2f(kg[cb + (size_t)tn * A_]);
          vb[j] = bf2f(vg[cb + (size_t)tn * A_]);
        }
        float ww2 = w + pp;
        float q2  = fmaxf(ww2, kk);
        float e1  = __expf(ww2 - q2);
        float e2  = __expf(kk  - q2);
        aa = e1*aa + e2*vv;
        bb = e1*bb + e2;
        pp = q2;
      }
    }
  }
  __shared__ float saa[WKV_C][WKV_G], sbb[WKV_C][WKV_G], spp[WKV_C][WKV_G];
  saa[c][al] = aa; sbb[c][al] = bb; spp[c][al] = pp;
  __syncthreads();

  // ---- combine: thread i (< WKV_G) walks chunks of channel i ----
  if (tid < WKV_G) {
    float Aa = 0.f, Bb = 0.f, Pp = -1e38f;
    const float Lw = (float)WKV_L * w;
    for (int cc = 0; cc < WKV_C; ++cc) {
      const float na = saa[cc][tid], nb = sbb[cc][tid], np = spp[cc][tid];
      saa[cc][tid] = Aa; sbb[cc][tid] = Bb; spp[cc][tid] = Pp;   // incoming prefix
      const float p1 = Pp + Lw;
      const float pc = fmaxf(p1, np);
      const float f1 = __expf(p1 - pc);
      const float f2 = __expf(np - pc);
      Aa = f1*Aa + f2*na;
      Bb = f1*Bb + f2*nb;
      Pp = pc;
    }
  }
  __syncthreads();
  aa = saa[c][al]; bb = sbb[c][al]; pp = spp[c][al];

  // ---- pass 2: outputs with true prefix state ----
  {
    float kb[4], vb[4], rb[4];
#pragma unroll
    for (int j = 0; j < 4; ++j) {
      kb[j] = bf2f(kg[cb + (size_t)j * A_]);
      vb[j] = bf2f(vg[cb + (size_t)j * A_]);
      rb[j] = bf2f(rg[cb + (size_t)j * A_]);
    }
    for (int t0 = 0; t0 < WKV_L; t0 += 4) {
#pragma unroll
      for (int j = 0; j < 4; ++j) {
        const float kk = kb[j], vv = vb[j], rr = rb[j];
        const int tn = t0 + j + 4;
        if (tn < WKV_L) {
          kb[j] = bf2f(kg[cb + (size_t)tn * A_]);
          vb[j] = bf2f(vg[cb + (size_t)tn * A_]);
          rb[j] = bf2f(rg[cb + (size_t)tn * A_]);
        }
        float ww = tf + kk;
        float q  = fmaxf(pp, ww);
        float e1 = __expf(pp - q);
        float e2 = __expf(ww - q);
        float o  = (e1*aa + e2*vv) / (e1*bb + e2);
        float sr = 1.f / (1.f + __expf(-rr));
        rwkv[cb + (size_t)(t0 + j) * A_] = f2bf(sr * o);
        float ww2 = w + pp;
        float q2  = fmaxf(ww2, kk);
        e1 = __expf(ww2 - q2);
        e2 = __expf(kk  - q2);
        aa = e1*aa + e2*vv;
        bb = e1*bb + e2;
        pp = q2;
      }
    }
  }
}

// ---------------- bf16 GEMM, BK=64, counted-vmcnt + frag-prefetch schedule ----------------
// A [M,lda] bf16 rm (reduction over K <= lda), Bt [N,lda] bf16 rm. BM x 256 tile,
// 512 thr, 8 waves (2M x 4N), per-wave (BM/2) x 64: FM = BM/32, FN = 4. NBUF LDS
// buffers; ONE barrier per K-tile (buffer swap). Counted vmcnt for NBUF=3 (6 loads
// stay in flight); NBUF=2 drains but last stage piece issued ~1 phase before wait.
// Both-sides 8-slot XOR swizzle on 128B rows (rule #21) -> conflict-free reads.
// BM=128 (r13): both kk-halves' 16 ds_reads up front, lgkm(8) -> 16 MFMA -> SP1 ->
// lgkm(0) -> 16 MFMA.  BM=256 (r14): sub-phase pipeline with counted lgkm.
// blockIdx.z batches independent GEMMs / split-K slices: byte strides azB/bzB/czB
// (lda decoupled from K enables split-K: A/B z-offset walks the K axis).
enum { EPI_BF16 = 0, EPI_ADDIP = 1, EPI_RELU2 = 2, EPI_SIGADD = 3 };

template <int BM, int NBUF, int RG, int CG, int EPI>
__global__ __launch_bounds__(512) void gemm4_kernel(
    const unsigned short* __restrict__ Ap, const unsigned short* __restrict__ Bp,
    void* __restrict__ Cp, int K, int Nn,
    const unsigned short* __restrict__ sigb,
    size_t azB, size_t bzB, size_t czB, int lda)
{
  constexpr int BN = 256;
  constexpr int FM = BM / 32;               // fragments per wave in M
  constexpr int FN = 4;
  __shared__ unsigned short As[NBUF * BM * 64];
  __shared__ unsigned short Bs[NBUF * BN * 64];
  const int zz = blockIdx.z;
  Ap = (const unsigned short*)((const char*)Ap + zz * azB);
  Bp = (const unsigned short*)((const char*)Bp + zz * bzB);
  Cp = (void*)((char*)Cp + zz * czB);
  const int tid  = threadIdx.x;
  const int lane = tid & 63;
  const int lr = lane & 15;
  const int hi = lane >> 4;                 // 0..3, selects 8-elem k-piece
  const int rx7 = lr & 7;                   // row&7 for fragment rows
  const int wid = tid >> 6;
  const int wm = wid >> 2, wn = wid & 3;    // 2M x 4N
  const int rowW = wm * (BM / 2);
  const int colW = wn * 64;
  // region-based XCD mapping (row-fastest within region)
  const int gx = gridDim.x;                 // col-tiles
  const int gy = gridDim.y;                 // row-tiles
  const int flat = blockIdx.y * gx + blockIdx.x;
  const int xcd = flat & 7;
  const int j = flat >> 3;                  // 0 .. RG*CG-1
  const int rgc = gy / RG;                  // row-group count (rgc * cgc == 8)
  const int r_idx = xcd % rgc;
  const int c_idx = xcd / rgc;
  const int row_l = j % RG;
  const int col_l = j / RG;
  const long row0 = (long)(r_idx * RG + row_l) * BM;
  const long col0 = (long)(c_idx * CG + col_l) * BN;
  const unsigned short* Ab = Ap + (size_t)row0 * lda;
  const unsigned short* Bb = Bp + (size_t)col0 * lda;
  const int srow8 = tid >> 3;               // 0..63
  const int sslot = (tid & 7) ^ (srow8 & 7);// permuted global source slot
  f32x4 acc[FM][FN] = {};

  // stage pieces:
  //  BM=128: SP0 = {A0, A1, B0} (3 loads), SP1 = {B1, B2, B3} (3 loads), 6/K-tile
  //  BM=256: SPq q=0..3: {A0A1},{A2A3},{B0B1},{B2B3} (2 loads each), 8/K-tile
  auto SP0 = [&](int bufi, int tt) {
    unsigned short* asb = As + bufi * (BM * 64);
    unsigned short* bsb = Bs + bufi * (BN * 64);
    const size_t ko = (size_t)tt * 64 + sslot * 8;
    gload_lds16(Ab + (size_t)srow8        * lda + ko, asb + tid * 8);
    gload_lds16(Ab + (size_t)(srow8 + 64) * lda + ko, asb + 4096 + tid * 8);
    gload_lds16(Bb + (size_t)srow8        * lda + ko, bsb + tid * 8);
  };
  auto SP1 = [&](int bufi, int tt) {
    unsigned short* bsb = Bs + bufi * (BN * 64);
    const size_t ko = (size_t)tt * 64 + sslot * 8;
    gload_lds16(Bb + (size_t)(srow8 + 64)  * lda + ko, bsb + 4096  + tid * 8);
    gload_lds16(Bb + (size_t)(srow8 + 128) * lda + ko, bsb + 8192  + tid * 8);
    gload_lds16(Bb + (size_t)(srow8 + 192) * lda + ko, bsb + 12288 + tid * 8);
  };
  auto SPq = [&](int bufi, int tt, int q) {
    const size_t ko = (size_t)tt * 64 + sslot * 8;
    if (q < 2) {
      unsigned short* asb = As + bufi * (BM * 64);
      gload_lds16(Ab + (size_t)(srow8 + q*128)      * lda + ko, asb + q*8192 + tid * 8);
      gload_lds16(Ab + (size_t)(srow8 + q*128 + 64) * lda + ko, asb + q*8192 + 4096 + tid * 8);
    } else {
      const int qq = q - 2;
      unsigned short* bsb = Bs + bufi * (BN * 64);
      gload_lds16(Bb + (size_t)(srow8 + qq*128)      * lda + ko, bsb + qq*8192 + tid * 8);
      gload_lds16(Bb + (size_t)(srow8 + qq*128 + 64) * lda + ko, bsb + qq*8192 + 4096 + tid * 8);
    }
  };

  const int nt = K >> 6;                    // K-tiles of 64
  if constexpr (BM == 128) {
    SP0(0, 0); SP1(0, 0);
    if constexpr (NBUF == 3) { SP0(1, 1); SP1(1, 1); }
  } else {
#pragma unroll
    for (int q = 0; q < 4; ++q) SPq(0, 0, q);
  }
  int cur = 0;
  for (int t = 0; t < nt; ++t) {
    if constexpr (NBUF == 3) {
      if (t + 1 < nt) asm volatile("s_waitcnt vmcnt(6)" ::: "memory");
      else            asm volatile("s_waitcnt vmcnt(0)" ::: "memory");
    } else {
      asm volatile("s_waitcnt vmcnt(0)" ::: "memory");
    }
    __builtin_amdgcn_s_barrier();           // ONLY barrier per K-tile (buffer swap)
    int nb = cur + (NBUF - 1); if (nb >= NBUF) nb -= NBUF;
    const unsigned short* asb = As + cur * (BM * 64);
    const unsigned short* bsb = Bs + cur * (BN * 64);
    if constexpr (BM == 128) {
      // r13 frag prefetch: issue BOTH kk-halves' reads, counted lgkm waits
      bf16x8 af0[4], bf0[4], af1[4], bf1[4];
      const int p0 = (0*4 + hi) ^ rx7;
      const int p1 = (1*4 + hi) ^ rx7;
#pragma unroll
      for (int m = 0; m < 4; ++m)
        af0[m] = __builtin_bit_cast(bf16x8,
            *(const short8*)(asb + (rowW + m*16 + lr) * 64 + p0*8));
#pragma unroll
      for (int n = 0; n < 4; ++n)
        bf0[n] = __builtin_bit_cast(bf16x8,
            *(const short8*)(bsb + (colW + n*16 + lr) * 64 + p0*8));
#pragma unroll
      for (int m = 0; m < 4; ++m)
        af1[m] = __builtin_bit_cast(bf16x8,
            *(const short8*)(asb + (rowW + m*16 + lr) * 64 + p1*8));
#pragma unroll
      for (int n = 0; n < 4; ++n)
        bf1[n] = __builtin_bit_cast(bf16x8,
            *(const short8*)(bsb + (colW + n*16 + lr) * 64 + p1*8));
      if (t + NBUF - 1 < nt) SP0(nb, t + NBUF - 1);
      asm volatile("s_waitcnt lgkmcnt(8)" ::: "memory");   // kk0's 8 reads done
      __builtin_amdgcn_sched_barrier(0);
      __builtin_amdgcn_s_setprio(1);
#pragma unroll
      for (int m = 0; m < 4; ++m)
#pragma unroll
        for (int n = 0; n < 4; ++n)
          acc[m][n] = __builtin_amdgcn_mfma_f32_16x16x32_bf16(af0[m], bf0[n], acc[m][n], 0, 0, 0);
      __builtin_amdgcn_s_setprio(0);
      if (t + NBUF - 1 < nt) SP1(nb, t + NBUF - 1);
      asm volatile("s_waitcnt lgkmcnt(0)" ::: "memory");   // kk1's reads done
      __builtin_amdgcn_sched_barrier(0);
      __builtin_amdgcn_s_setprio(1);
#pragma unroll
      for (int m = 0; m < 4; ++m)
#pragma unroll
        for (int n = 0; n < 4; ++n)
          acc[m][n] = __builtin_amdgcn_mfma_f32_16x16x32_bf16(af1[m], bf1[n], acc[m][n], 0, 0, 0);
      __builtin_amdgcn_s_setprio(0);
    } else {
      // sub-phase pipeline (r14): subs = (kk0,mh0),(kk0,mh1),(kk1,mh0),(kk1,mh1)
      bf16x8 aF[2][4], bF[2][4];
      const int p0 = (0*4 + hi) ^ rx7;
      const int p1 = (1*4 + hi) ^ rx7;
#pragma unroll
      for (int n = 0; n < 4; ++n)
        bF[0][n] = __builtin_bit_cast(bf16x8,
            *(const short8*)(bsb + (colW + n*16 + lr) * 64 + p0*8));
#pragma unroll
      for (int m = 0; m < 4; ++m)
        aF[0][m] = __builtin_bit_cast(bf16x8,
            *(const short8*)(asb + (rowW + m*16 + lr) * 64 + p0*8));
#pragma unroll
      for (int m = 0; m < 4; ++m)
        aF[1][m] = __builtin_bit_cast(bf16x8,
            *(const short8*)(asb + (rowW + (4+m)*16 + lr) * 64 + p0*8));
      if (t + 1 < nt) SPq(nb, t + 1, 0);
      asm volatile("s_waitcnt lgkmcnt(4)" ::: "memory");
      __builtin_amdgcn_sched_barrier(0);
      __builtin_amdgcn_s_setprio(1);
#pragma unroll
      for (int m = 0; m < 4; ++m)
#pragma unroll
        for (int n = 0; n < 4; ++n)
          acc[m][n] = __builtin_amdgcn_mfma_f32_16x16x32_bf16(aF[0][m], bF[0][n], acc[m][n], 0, 0, 0);
      __builtin_amdgcn_s_setprio(0);
#pragma unroll
      for (int n = 0; n < 4; ++n)
        bF[1][n] = __builtin_bit_cast(bf16x8,
            *(const short8*)(bsb + (colW + n*16 + lr) * 64 + p1*8));
#pragma unroll
      for (int m = 0; m < 4; ++m)
        aF[0][m] = __builtin_bit_cast(bf16x8,
            *(const short8*)(asb + (rowW + m*16 + lr) * 64 + p1*8));
      if (t + 1 < nt) SPq(nb, t + 1, 1);
      asm volatile("s_waitcnt lgkmcnt(8)" ::: "memory");
      __builtin_amdgcn_sched_barrier(0);
      __builtin_amdgcn_s_setprio(1);
#pragma unroll
      for (int m = 0; m < 4; ++m)
#pragma unroll
        for (int n = 0; n < 4; ++n)
          acc[4+m][n] = __builtin_amdgcn_mfma_f32_16x16x32_bf16(aF[1][m], bF[0][n], acc[4+m][n], 0, 0, 0);
      __builtin_amdgcn_s_setprio(0);
#pragma unroll
      for (int m = 0; m < 4; ++m)
        aF[1][m] = __builtin_bit_cast(bf16x8,
            *(const short8*)(asb + (rowW + (4+m)*16 + lr) * 64 + p1*8));
      if (t + 1 < nt) SPq(nb, t + 1, 2);
      asm volatile("s_waitcnt lgkmcnt(4)" ::: "memory");
      __builtin_amdgcn_sched_barrier(0);
      __builtin_amdgcn_s_setprio(1);
#pragma unroll
      for (int m = 0; m < 4; ++m)
#pragma unroll
        for (int n = 0; n < 4; ++n)
          acc[m][n] = __builtin_amdgcn_mfma_f32_16x16x32_bf16(aF[0][m], bF[1][n], acc[m][n], 0, 0, 0);
      __builtin_amdgcn_s_setprio(0);
      if (t + 1 < nt) SPq(nb, t + 1, 3);
      asm volatile("s_waitcnt lgkmcnt(0)" ::: "memory");
      __builtin_amdgcn_sched_barrier(0);
      __builtin_amdgcn_s_setprio(1);
#pragma unroll
      for (int m = 0; m < 4; ++m)
#pragma unroll
        for (int n = 0; n < 4; ++n)
          acc[4+m][n] = __builtin_amdgcn_mfma_f32_16x16x32_bf16(aF[1][m], bF[1][n], acc[4+m][n], 0, 0, 0);
      __builtin_amdgcn_s_setprio(0);
    }
    cur = (cur + 1 == NBUF) ? 0 : cur + 1;
  }

  // C/D layout: col = lane&15, row = (lane>>4)*4 + j
#pragma unroll
  for (int m = 0; m < FM; ++m) {
#pragma unroll
    for (int n = 0; n < FN; ++n) {
      const long col = col0 + colW + n*16 + lr;
#pragma unroll
      for (int j2 = 0; j2 < 4; ++j2) {
        const long row = row0 + rowW + m*16 + hi*4 + j2;
        const size_t idx = (size_t)row * Nn + col;
        const float v = acc[m][n][j2];
        if (EPI == EPI_BF16) {
          ((unsigned short*)Cp)[idx] = f2bf(v);
        } else if (EPI == EPI_ADDIP) {
          float* C = (float*)Cp;
          C[idx] = C[idx] + v;                       // in-place residual add
        } else if (EPI == EPI_RELU2) {
          float rr = v > 0.f ? v : 0.f;
          ((unsigned short*)Cp)[idx] = f2bf(rr * rr);
        } else {                                     // EPI_SIGADD
          float s = 1.f / (1.f + __expf(-bf2f(sigb[idx])));
          float* C = (float*)Cp;
          C[idx] = C[idx] + s * v;
        }
      }
    }
  }
}

// ---------------- workspace layout (MB) ----------------
// 0..48   mix3 outputs kx/vx/rx (16MB each)  -> later fWkT@0..32, fWvT@32..64
// 64..72  WkT   72..80 WvT   80..88 WrT   88..96 WoT   96..104 fWrT
// 104..120 S1 (x1 -> rwkv)
// 120..136 kbuf (k -> rx2)  136..152 vbuf (v -> r2pre)  152..184 PK (split-K partials,
//   aliases rbuf(152..168)=r and M1(168..184)=kx2, both dead by split-K time)
// KK (kk2 [4096,8192] bf16, 64MB) aliases 64..128, all dead by the FF GEMMs.
#define MB(x) ((size_t)(x) << 20)
#define WS_NEED MB(184)

extern "C" void kernel_launch(void* const* d_in, const int* in_sizes, int n_in,
                              void* d_out, int out_size, void* d_ws, size_t ws_size,
                              hipStream_t stream) {
  const float* hidden     = (const float*)d_in[0];
  const float* pre_w      = (const float*)d_in[1];
  const float* pre_b      = (const float*)d_in[2];
  const float* ln1_w      = (const float*)d_in[3];
  const float* ln1_b      = (const float*)d_in[4];
  const float* ln2_w      = (const float*)d_in[5];
  const float* ln2_b      = (const float*)d_in[6];
  const float* time_decay = (const float*)d_in[7];
  const float* time_first = (const float*)d_in[8];
  const float* tmk        = (const float*)d_in[9];
  const float* tmv        = (const float*)d_in[10];
  const float* tmr        = (const float*)d_in[11];
  const float* Wk         = (const float*)d_in[12];
  const float* Wv         = (const float*)d_in[13];
  const float* Wr         = (const float*)d_in[14];
  const float* Wo         = (const float*)d_in[15];
  const float* f_tmk      = (const float*)d_in[16];
  const float* f_tmr      = (const float*)d_in[17];
  const float* f_Wk       = (const float*)d_in[18];
  const float* f_Wr       = (const float*)d_in[19];
  const float* f_Wv       = (const float*)d_in[20];
  float* out = (float*)d_out;
  char*  ws  = (char*)d_ws;

  if (ws_size < WS_NEED) {               // diagnostic canary: absmax ~1000 => ws too small
    canary_kernel<<<1, 256, 0, stream>>>(out);
    return;
  }

  unsigned short* MX   = (unsigned short*)(ws + MB(0));    // kx/vx/rx (3 x 16MB)
  unsigned short* fWkT = (unsigned short*)(ws + MB(0));    // after mixes dead
  unsigned short* fWvT = (unsigned short*)(ws + MB(32));
  unsigned short* WkT  = (unsigned short*)(ws + MB(64));   // Wk/Wv/Wr contiguous for z-stride
  unsigned short* WoT  = (unsigned short*)(ws + MB(88));
  unsigned short* fWrT = (unsigned short*)(ws + MB(96));
  unsigned short* KK   = (unsigned short*)(ws + MB(64));   // kk2 full, aliases dead data
  unsigned short* S1   = (unsigned short*)(ws + MB(104));  // x1 -> rwkv
  unsigned short* kbuf = (unsigned short*)(ws + MB(120));  // k -> rx2
  unsigned short* vbuf = (unsigned short*)(ws + MB(136));  // v -> r2pre
  unsigned short* rbuf = (unsigned short*)(ws + MB(152));  // r
  unsigned short* M1   = (unsigned short*)(ws + MB(168));  // kx2
  unsigned short* PK   = (unsigned short*)(ws + MB(152));  // split-K partials (2x16MB)

  const dim3 blk(256);
  const dim3 blk512(512);
  const dim3 gSmall(8, 32);      // 128x256 tile over [4096,2048] -> 256 blocks
  const dim3 gSmall3(8, 32, 3);  // 3 batched projections (BM=128)
  const dim3 gBig2(8, 16, 2);    // 256x256 tile, split-K=2 -> 256 blocks
  const dim3 gRelu(32, 16);      // 256x256 tile over [4096,8192] -> 512 blocks

  // 1) five small weight transposes in ONE z=5 dispatch (vectorized 64x64 tiles)
  transpose5_kernel<<<dim3(32, 32, 5), blk, 0, stream>>>(Wk, Wv, Wr, Wo, f_Wr, WkT);

  // 2) pre-LN + LN1: h0 -> d_out (fp32), x1 -> S1 (bf16)
  ln_pre_kernel<<<BT_, blk, 0, stream>>>(hidden, pre_w, pre_b, ln1_w, ln1_b, out, S1);

  // 3) one mix pass (kx/vx/rx) + one batched z=3 GEMM: {k,v,r} = mix @ {Wk,Wv,Wr}^T
  mix3_kernel<<<BT_, blk, 0, stream>>>(S1, tmk, tmv, tmr, MX, MX + (MB(16)>>1), MX + (MB(32)>>1));
  gemm4_kernel<128,3,8,4,EPI_BF16><<<gSmall3, blk512, 0, stream>>>(
      MX, WkT, kbuf, 2048, 2048, nullptr, MB(16), MB(8), MB(16), 2048);

  // 4) deferred big transposes (mix buffers now dead), vectorized
  transpose_bf16_kernel<<<dim3(128, 32), blk, 0, stream>>>(f_Wk, fWkT, 2048, 8192);
  transpose_bf16_kernel<<<dim3(32, 128), blk, 0, stream>>>(f_Wv, fWvT, 8192, 2048);

  // 5) chunk-parallel WKV scan (256 blocks, 4096 waves) + sigmoid(r)*wkv -> S1
  wkv_scan_kernel<<<dim3(256), dim3(1024), 0, stream>>>(kbuf, vbuf, rbuf, time_first, time_decay, S1);

  // 6) h1 = h0 + rwkv @ Wo  (in-place on d_out)
  gemm4_kernel<128,3,8,4,EPI_ADDIP><<<gSmall, blk512, 0, stream>>>(
      S1, WoT, out, 2048, 2048, nullptr, 0, 0, 0, 2048);

  // 7) fused LN2 + FF mixes: kx2 -> M1, rx2 -> kbuf (x2 never materialized)
  lnmix2_kernel<<<BT_, blk, 0, stream>>>(out, ln2_w, ln2_b, f_tmk, f_tmr, M1, kbuf);

  // 8) r2pre = rx2 @ f_Wr -> vbuf
  gemm4_kernel<128,3,8,4,EPI_BF16><<<gSmall, blk512, 0, stream>>>(
      kbuf, fWrT, vbuf, 2048, 2048, nullptr, 0, 0, 0, 2048);

  // 9) FF: kk2 = relu(kx2@f_Wk)^2 -> KK  (256x256 tile, sub-phase pipelined)
  gemm4_kernel<256,2,8,8,EPI_RELU2><<<gRelu, blk512, 0, stream>>>(
      M1, fWkT, KK, 2048, 8192, nullptr, 0, 0, 0, 2048);

  // 10) split-K=2 (BM=256, full machine): P{0,1} = kk2[:, z*4096:] @ f_WvT -> PK bf16
  gemm4_kernel<256,2,8,2,EPI_BF16><<<gBig2, blk512, 0, stream>>>(
      KK, fWvT, PK, 4096, 2048, nullptr, (size_t)4096*2, (size_t)4096*2, MB(16), 8192);

  // 11) out += sigmoid(r2pre) * (P0 + P1)
  sigcombine_kernel<<<dim3(4096), blk, 0, stream>>>(PK, PK + (MB(16)>>1), vbuf, out);
}